// Round 2
// baseline (987.773 us; speedup 1.0000x reference)
//
#include <hip/hip_runtime.h>
#include <hip/hip_bf16.h>
#include <cstdint>

using bf16 = __hip_bfloat16;

static constexpr int B = 2;
static constexpr int N = 2048;
static constexpr int KNN = 32;
static constexpr int FD = 480;
static constexpr float EPS = 1e-5f;
static constexpr float SLOPE = 0.2f;

// ---------------- workspace layout (floats), all compile-time ----------------
static constexpr size_t N_XF = (size_t)B * N * 3;
static constexpr size_t N_FEATS = (size_t)B * N * FD;
static constexpr size_t N_DIST = (size_t)B * N * N;
static constexpr size_t N_IDX = (size_t)B * N * KNN;
static constexpr size_t N_PROJ = (size_t)B * N * 512;  // proj [BN][2O], O<=256
static constexpr size_t O_XF = 0;
static constexpr size_t O_FEATS = O_XF + N_XF;
static constexpr size_t O_DIST = O_FEATS + N_FEATS;
static constexpr size_t O_IDX = O_DIST + N_DIST;
static constexpr size_t O_PROJ = O_IDX + N_IDX;
static constexpr size_t O_WP0 = O_PROJ + N_PROJ;      // [3][64]
static constexpr size_t O_WP1 = O_WP0 + 192;          // [32][128]
static constexpr size_t O_WP2 = O_WP1 + 4096;         // [64][256]
static constexpr size_t O_WP3 = O_WP2 + 16384;        // [128][512]
static constexpr size_t O_WHT = O_WP3 + 65536;
static constexpr size_t O_F1W = O_WHT + 61440;
static constexpr size_t O_F1B = O_F1W + 16384;
static constexpr size_t O_F2W = O_F1B + 128;
static constexpr size_t O_F2B = O_F2W + 16384;
static constexpr size_t O_FLAG = O_F2B + 128;
static constexpr size_t O_CS0 = O_FLAG + 16;   // zero region starts here
static constexpr size_t O_CS1 = O_CS0 + 128;
static constexpr size_t O_CS2 = O_CS1 + 256;
static constexpr size_t O_CS3 = O_CS2 + 512;
static constexpr size_t O_FSUM = O_CS3 + 1024;
static constexpr size_t O_FSS = O_FSUM + 256;
static constexpr size_t O_FMAX = O_FSS + 256;
static constexpr size_t O_END = O_FMAX + 256;
static constexpr size_t N_ZERO = O_END - O_CS0;

__device__ __forceinline__ float lrelu(float x) { return x >= 0.f ? x : SLOPE * x; }

__device__ __forceinline__ float load_in(const void* p, int i, int isf32) {
  return isf32 ? ((const float*)p)[i] : __bfloat162float(((const bf16*)p)[i]);
}

// ---------------------------------------------------------------- prep (fused)
static constexpr int PREP_TOTAL =
    (int)(N_XF + 96 + 2048 + 8192 + 32768 + 61440 + 16384 + 128 + 16384 + 128 + N_ZERO);

__global__ __launch_bounds__(256) void prep_kernel(
    const void* __restrict__ x, const void* __restrict__ W0, const void* __restrict__ W1,
    const void* __restrict__ W2, const void* __restrict__ W3, const void* __restrict__ Wh,
    const void* __restrict__ fc1w, const void* __restrict__ fc1b,
    const void* __restrict__ fc2w, const void* __restrict__ fc2b, float* __restrict__ ws) {
  __shared__ float red[256];
  const unsigned short* xr = (const unsigned short*)x;
  float mx = 0.f;
  for (int i = threadIdx.x; i < B * N * 3; i += 256) {
    float v = __uint_as_float(((unsigned)xr[i]) << 16);
    v = fabsf(v);
    if (!(v < 1e30f)) v = 1e30f;  // NaN/inf -> huge
    mx = fmaxf(mx, v);
  }
  red[threadIdx.x] = mx;
  __syncthreads();
  for (int s = 128; s > 0; s >>= 1) {
    if (threadIdx.x < s) red[threadIdx.x] = fmaxf(red[threadIdx.x], red[threadIdx.x + s]);
    __syncthreads();
  }
  int isf = red[0] > 1e3f ? 1 : 0;
  if (blockIdx.x == 0 && threadIdx.x == 0) ((int*)(ws + O_FLAG))[0] = isf;

  int idx = blockIdx.x * 256 + threadIdx.x;
  if (idx < (int)N_XF) { ws[O_XF + idx] = load_in(x, idx, isf); return; }
  idx -= (int)N_XF;
  if (idx < 96) {  // W0: O=32,C=3
    int o = idx / 3, c = idx - o * 3;
    float a = load_in(W0, o * 6 + c, isf);
    float bb = load_in(W0, o * 6 + 3 + c, isf);
    ws[O_WP0 + c * 64 + o] = a;
    ws[O_WP0 + c * 64 + 32 + o] = bb - a;
    return;
  }
  idx -= 96;
  if (idx < 2048) {  // W1: O=64,C=32
    int o = idx >> 5, c = idx & 31;
    float a = load_in(W1, o * 64 + c, isf);
    float bb = load_in(W1, o * 64 + 32 + c, isf);
    ws[O_WP1 + c * 128 + o] = a;
    ws[O_WP1 + c * 128 + 64 + o] = bb - a;
    return;
  }
  idx -= 2048;
  if (idx < 8192) {  // W2: O=128,C=64
    int o = idx >> 6, c = idx & 63;
    float a = load_in(W2, o * 128 + c, isf);
    float bb = load_in(W2, o * 128 + 64 + c, isf);
    ws[O_WP2 + c * 256 + o] = a;
    ws[O_WP2 + c * 256 + 128 + o] = bb - a;
    return;
  }
  idx -= 8192;
  if (idx < 32768) {  // W3: O=256,C=128
    int o = idx >> 7, c = idx & 127;
    float a = load_in(W3, o * 256 + c, isf);
    float bb = load_in(W3, o * 256 + 128 + c, isf);
    ws[O_WP3 + c * 512 + o] = a;
    ws[O_WP3 + c * 512 + 256 + o] = bb - a;
    return;
  }
  idx -= 32768;
  if (idx < 61440) {  // Wh [128][480] -> [480][128]
    int o = idx / 480, c = idx - o * 480;
    ws[O_WHT + c * 128 + o] = load_in(Wh, idx, isf);
    return;
  }
  idx -= 61440;
  if (idx < 16384) { ws[O_F1W + idx] = load_in(fc1w, idx, isf); return; }
  idx -= 16384;
  if (idx < 128) { ws[O_F1B + idx] = load_in(fc1b, idx, isf); return; }
  idx -= 128;
  if (idx < 16384) { ws[O_F2W + idx] = load_in(fc2w, idx, isf); return; }
  idx -= 16384;
  if (idx < 128) { ws[O_F2B + idx] = load_in(fc2b, idx, isf); return; }
  idx -= 128;
  if (idx < (int)N_ZERO) ws[O_CS0 + idx] = 0.f;
}

// ---------------------------------------------------------------- dist (sq fused)
// R14: fragment reads via ds_read_b128; B-tile split into two 4-wide quads at
// tx*4 and 64+tx*4 so lane addresses stride 4 words (2-way bank alias = free)
// instead of stride 8 (4-way conflict).
template <int C>
__global__ __launch_bounds__(256) void dist_kernel(const float* __restrict__ h, int hstride,
                                                   float* __restrict__ dist) {
  constexpr int CW = 16;
  __shared__ float Ast[CW][132];
  __shared__ float Bst[CW][132];
  __shared__ float sqn[128], sqm[128];
  int b = blockIdx.z;
  int n0 = blockIdx.y * 128, m0 = blockIdx.x * 128;
  int tid = threadIdx.x;
  int tx = tid & 15, ty = tid >> 4;
  int rr = tid & 127;
  float dot[8][8] = {};
  float sqacc = 0.f;
  for (int cc = 0; cc < C; cc += CW) {
    for (int i = tid; i < 128 * CW; i += 256) {
      int c = i & 15, r = i >> 4;
      int gc = cc + c;
      float av = 0.f, bv = 0.f;
      if (gc < C) {
        av = h[(size_t)(b * N + n0 + r) * hstride + gc];
        bv = h[(size_t)(b * N + m0 + r) * hstride + gc];
      }
      Ast[c][r] = av;
      Bst[c][r] = bv;
    }
    __syncthreads();
    if (tid < 128) {
#pragma unroll
      for (int c = 0; c < CW; ++c) { float v = Ast[c][rr]; sqacc += v * v; }
    } else {
#pragma unroll
      for (int c = 0; c < CW; ++c) { float v = Bst[c][rr]; sqacc += v * v; }
    }
#pragma unroll
    for (int c = 0; c < CW; ++c) {
      float4 a0 = *reinterpret_cast<const float4*>(&Ast[c][ty * 8]);
      float4 a1 = *reinterpret_cast<const float4*>(&Ast[c][ty * 8 + 4]);
      float4 b0 = *reinterpret_cast<const float4*>(&Bst[c][tx * 4]);
      float4 b1 = *reinterpret_cast<const float4*>(&Bst[c][64 + tx * 4]);
      float av[8] = {a0.x, a0.y, a0.z, a0.w, a1.x, a1.y, a1.z, a1.w};
      float bv[8] = {b0.x, b0.y, b0.z, b0.w, b1.x, b1.y, b1.z, b1.w};
#pragma unroll
      for (int i = 0; i < 8; ++i)
#pragma unroll
        for (int j = 0; j < 8; ++j) dot[i][j] += av[i] * bv[j];
    }
    __syncthreads();
  }
  if (tid < 128) sqn[rr] = sqacc; else sqm[rr] = sqacc;
  __syncthreads();
#pragma unroll
  for (int i = 0; i < 8; ++i) {
    int nn = n0 + ty * 8 + i;
    float sn = sqn[ty * 8 + i];
    float4 w;
    w.x = sn + sqm[tx * 4 + 0] - 2.f * dot[i][0];
    w.y = sn + sqm[tx * 4 + 1] - 2.f * dot[i][1];
    w.z = sn + sqm[tx * 4 + 2] - 2.f * dot[i][2];
    w.w = sn + sqm[tx * 4 + 3] - 2.f * dot[i][3];
    *reinterpret_cast<float4*>(&dist[(size_t)(b * N + nn) * N + m0 + tx * 4]) = w;
    float4 w2;
    w2.x = sn + sqm[64 + tx * 4 + 0] - 2.f * dot[i][4];
    w2.y = sn + sqm[64 + tx * 4 + 1] - 2.f * dot[i][5];
    w2.z = sn + sqm[64 + tx * 4 + 2] - 2.f * dot[i][6];
    w2.w = sn + sqm[64 + tx * 4 + 3] - 2.f * dot[i][7];
    *reinterpret_cast<float4*>(&dist[(size_t)(b * N + nn) * N + m0 + 64 + tx * 4]) = w2;
  }
}

__device__ __forceinline__ unsigned long long wave_min_u64(unsigned long long v) {
#pragma unroll
  for (int m = 1; m < 64; m <<= 1) {
    unsigned lo = (unsigned)v;
    unsigned hi = (unsigned)(v >> 32);
    unsigned olo = (unsigned)__shfl_xor((int)lo, m, 64);
    unsigned ohi = (unsigned)__shfl_xor((int)hi, m, 64);
    unsigned long long ov = ((unsigned long long)ohi << 32) | olo;
    if (ov < v) v = ov;
  }
  return v;
}

// R14: tree argmin over 32 register keys — 4 independent 8-chains + 3-level
// merge. Same inst count as the old sequential scan but dep chain 64 -> ~27.
#define ARGMIN32(dk, ld, lj)                                        \
  {                                                                 \
    unsigned kv0 = dk[0], kv1 = dk[8], kv2 = dk[16], kv3 = dk[24];  \
    int j0 = 0, j1 = 8, j2 = 16, j3 = 24;                           \
    _Pragma("unroll")                                               \
    for (int t = 1; t < 8; ++t) {                                   \
      if (dk[t] < kv0) { kv0 = dk[t]; j0 = t; }                     \
      if (dk[8 + t] < kv1) { kv1 = dk[8 + t]; j1 = 8 + t; }         \
      if (dk[16 + t] < kv2) { kv2 = dk[16 + t]; j2 = 16 + t; }      \
      if (dk[24 + t] < kv3) { kv3 = dk[24 + t]; j3 = 24 + t; }      \
    }                                                               \
    if (kv1 < kv0) { kv0 = kv1; j0 = j1; }                          \
    if (kv3 < kv2) { kv2 = kv3; j2 = j3; }                          \
    if (kv2 < kv0) { kv0 = kv2; j0 = j2; }                          \
    ld = kv0; lj = j0;                                              \
  }

// ---------------------------------------------------------------- fused select || proj
template <int C, int NO2>
__global__ __launch_bounds__(256) void selproj_kernel(const float* __restrict__ dist,
                                                      int* __restrict__ idxb,
                                                      const float* __restrict__ h,
                                                      int hstride,
                                                      const float* __restrict__ Wp,
                                                      float* __restrict__ projb) {
  constexpr int NSEL = B * N / 4;
  constexpr int MT = NO2 / 64;
  constexpr int CW = 16;
  __shared__ float As[64][17];
  __shared__ float Bs[64][17];
  if (blockIdx.x < NSEL) {
    int row = blockIdx.x * 4 + (threadIdx.x >> 6);  // b*N + n
    int lane = threadIdx.x & 63;
    const float* drow = dist + (size_t)row * N;
    unsigned dk[32];
#pragma unroll
    for (int j = 0; j < 32; ++j) {
      unsigned u = __float_as_uint(drow[j * 64 + lane]);
      dk[j] = (u & 0x80000000u) ? ~u : (u | 0x80000000u);
    }
    unsigned ld;
    int lj;
    ARGMIN32(dk, ld, lj);
    unsigned saved = 0;
    for (int it = 0; it <= KNN; ++it) {
      unsigned long long lkey =
          ((unsigned long long)ld << 32) | (unsigned)(lj * 64 + lane);
      unsigned long long g = wave_min_u64(lkey);
      if (it > 0 && lane == it - 1) saved = (unsigned)(g & 0xFFFFFFFFull);
      if (lkey == g) {  // unique m per lane -> exactly one winner
#pragma unroll
        for (int j = 0; j < 32; ++j)
          if (j == lj) dk[j] = 0xFFFFFFFFu;
        ARGMIN32(dk, ld, lj);
      }
    }
    if (lane < KNN) idxb[row * KNN + lane] = (int)saved;
  } else {
    int tile = blockIdx.x - NSEL;
    int m0 = (tile % MT) * 64;
    int n0 = (tile / MT) * 64;
    int tid = threadIdx.x;
    int tx = tid & 15, ty = tid >> 4;
    float dot[4][4] = {};
    for (int cc = 0; cc < C; cc += CW) {
      for (int i = tid; i < 64 * CW; i += 256) {
        int r = i >> 4, c = i & 15;
        int gc = cc + c;
        As[r][c] = (gc < C) ? h[(size_t)(n0 + r) * hstride + gc] : 0.f;
      }
      for (int i = tid; i < 64 * CW; i += 256) {
        int c = i >> 6, m = i & 63;
        int gc = cc + c;
        Bs[m][c] = (gc < C) ? Wp[(size_t)gc * NO2 + m0 + m] : 0.f;
      }
      __syncthreads();
#pragma unroll
      for (int c = 0; c < CW; ++c) {
        float av[4], bv[4];
#pragma unroll
        for (int i = 0; i < 4; ++i) av[i] = As[ty * 4 + i][c];
#pragma unroll
        for (int j = 0; j < 4; ++j) bv[j] = Bs[tx * 4 + j][c];
#pragma unroll
        for (int i = 0; i < 4; ++i)
#pragma unroll
          for (int j = 0; j < 4; ++j) dot[i][j] += av[i] * bv[j];
      }
      __syncthreads();
    }
#pragma unroll
    for (int i = 0; i < 4; ++i) {
      float4 w;
      w.x = dot[i][0];
      w.y = dot[i][1];
      w.z = dot[i][2];
      w.w = dot[i][3];
      *reinterpret_cast<float4*>(&projb[(size_t)(n0 + ty * 4 + i) * NO2 + m0 + tx * 4]) = w;
    }
  }
}

// ---------------------------------------------------------------- edge reduce
// R15: one wave per point. lane=(g,q): group g owns KS=KNN/G neighbors, quad q.
// All per-k reductions in registers; cross-group via shfl_xor butterfly; the
// only barriers are knn staging and the final cross-wave stats reduce. Gathers
// are software-pipelined in two 8-deep float4 buffers -> up to 16 rows in
// flight per wave with no barrier ever draining them (old: 8 barriers/block
// drained vmem 4x per block -> 143us @ 3.5% HBM, VALUBusy 1.9%).
template <int O>
__global__ __launch_bounds__(256) void edge_reduce_kernel(const float* __restrict__ proj,
                                                          const int* __restrict__ idxb,
                                                          float* __restrict__ cstats,
                                                          float* __restrict__ featdst) {
  constexpr int Q = O / 4;        // float4 quads per half-row (8..64)
  constexpr int G = 64 / Q;       // k-groups per wave (8..1)
  constexpr int KS = KNN / G;     // neighbors per lane (4..32)
  constexpr int NW = 4;           // waves per block, one bn per wave
  constexpr int NO2 = 2 * O;
  __shared__ int knn[NW * KNN];
  __shared__ float4 red2[2][NW][Q];
  int bn0 = blockIdx.x * NW;
  int b = bn0 >> 11;
  int tid = threadIdx.x;
  int w = tid >> 6;
  int lane = tid & 63;
  int g = lane / Q;
  int q = lane - g * Q;
  if (tid < NW * KNN) knn[tid] = idxb[bn0 * KNN + tid];
  __syncthreads();
  int bn = bn0 + w;
  int jbase = b << 11;  // knn indices are within-batch; proj rows are global bn
  const float4 h0 = *reinterpret_cast<const float4*>(&proj[(size_t)bn * NO2 + O + q * 4]);
  float4 mx = {-3.4e38f, -3.4e38f, -3.4e38f, -3.4e38f};
  float4 s = {0.f, 0.f, 0.f, 0.f}, ss = {0.f, 0.f, 0.f, 0.f};
  const int kb = w * KNN + g * KS;

  auto gat = [&](int t) -> float4 {
    int j = jbase + knn[kb + t];
    return *reinterpret_cast<const float4*>(&proj[(size_t)j * NO2 + q * 4]);
  };
  auto acc = [&](const float4& v) {
    float ex = v.x + h0.x, ey = v.y + h0.y, ez = v.z + h0.z, ew = v.w + h0.w;
    s.x += ex; ss.x += ex * ex; mx.x = fmaxf(mx.x, ex);
    s.y += ey; ss.y += ey * ey; mx.y = fmaxf(mx.y, ey);
    s.z += ez; ss.z += ez * ez; mx.z = fmaxf(mx.z, ez);
    s.w += ew; ss.w += ew * ew; mx.w = fmaxf(mx.w, ew);
  };

  if constexpr (KS <= 8) {
    float4 v[KS];
#pragma unroll
    for (int t = 0; t < KS; ++t) v[t] = gat(t);
#pragma unroll
    for (int t = 0; t < KS; ++t) acc(v[t]);
  } else {
    float4 va[8], vb[8];
#pragma unroll
    for (int t = 0; t < 8; ++t) va[t] = gat(t);
#pragma unroll
    for (int t = 0; t < 8; ++t) vb[t] = gat(8 + t);
#pragma unroll
    for (int t = 0; t < 8; ++t) acc(va[t]);
    if constexpr (KS == 32) {
#pragma unroll
      for (int t = 0; t < 8; ++t) va[t] = gat(16 + t);
    }
#pragma unroll
    for (int t = 0; t < 8; ++t) acc(vb[t]);
    if constexpr (KS == 32) {
#pragma unroll
      for (int t = 0; t < 8; ++t) vb[t] = gat(24 + t);
#pragma unroll
      for (int t = 0; t < 8; ++t) acc(va[t]);
#pragma unroll
      for (int t = 0; t < 8; ++t) acc(vb[t]);
    }
  }

  if constexpr (G > 1) {
#pragma unroll
    for (int m = Q; m < 64; m <<= 1) {
      mx.x = fmaxf(mx.x, __shfl_xor(mx.x, m, 64));
      mx.y = fmaxf(mx.y, __shfl_xor(mx.y, m, 64));
      mx.z = fmaxf(mx.z, __shfl_xor(mx.z, m, 64));
      mx.w = fmaxf(mx.w, __shfl_xor(mx.w, m, 64));
      s.x += __shfl_xor(s.x, m, 64);
      s.y += __shfl_xor(s.y, m, 64);
      s.z += __shfl_xor(s.z, m, 64);
      s.w += __shfl_xor(s.w, m, 64);
      ss.x += __shfl_xor(ss.x, m, 64);
      ss.y += __shfl_xor(ss.y, m, 64);
      ss.z += __shfl_xor(ss.z, m, 64);
      ss.w += __shfl_xor(ss.w, m, 64);
    }
  }
  if (lane < Q) {
    *reinterpret_cast<float4*>(&featdst[(size_t)bn * FD + q * 4]) = mx;
    red2[0][w][q] = s;
    red2[1][w][q] = ss;
  }
  __syncthreads();
  if (tid < Q) {
    float4 t0 = red2[0][0][tid], t1 = red2[1][0][tid];
#pragma unroll
    for (int r = 1; r < NW; ++r) {
      float4 a0 = red2[0][r][tid], a1 = red2[1][r][tid];
      t0.x += a0.x; t0.y += a0.y; t0.z += a0.z; t0.w += a0.w;
      t1.x += a1.x; t1.y += a1.y; t1.z += a1.z; t1.w += a1.w;
    }
    int o = tid * 4;
    atomicAdd(&cstats[(b * O + o + 0) * 2 + 0], t0.x);
    atomicAdd(&cstats[(b * O + o + 0) * 2 + 1], t1.x);
    atomicAdd(&cstats[(b * O + o + 1) * 2 + 0], t0.y);
    atomicAdd(&cstats[(b * O + o + 1) * 2 + 1], t1.y);
    atomicAdd(&cstats[(b * O + o + 2) * 2 + 0], t0.z);
    atomicAdd(&cstats[(b * O + o + 2) * 2 + 1], t1.z);
    atomicAdd(&cstats[(b * O + o + 3) * 2 + 0], t0.w);
    atomicAdd(&cstats[(b * O + o + 3) * 2 + 1], t1.w);
  }
}

// in-place: featdst = lrelu((featdst - mean) * rsqrt(var + eps))
__global__ void finalize_kernel(const float* __restrict__ cstats,
                                float* __restrict__ featdst, int O) {
  int i = blockIdx.x * 256 + threadIdx.x;
  int o = i % O;
  int bn = i / O;
  int b = bn >> 11;
  float s = cstats[(b * O + o) * 2 + 0];
  float ss = cstats[(b * O + o) * 2 + 1];
  constexpr float inv = 1.f / ((float)N * KNN);
  float m = s * inv;
  float v = fmaxf(ss * inv - m * m, 0.f);
  float* p = &featdst[(size_t)bn * FD + o];
  float e = (*p - m) * rsqrtf(v + EPS);
  *p = lrelu(e);
}

// ---------------------------------------------------------------- 480 -> 128 stage
__global__ __launch_bounds__(256) void fstage_kernel(const float* __restrict__ feats,
                                                     const float* __restrict__ Wht,
                                                     float* __restrict__ fsum,
                                                     float* __restrict__ fss,
                                                     unsigned* __restrict__ fmaxu) {
  int blk = blockIdx.x;
  int b = blk >> 7;
  int n0 = (blk & 127) * 16;
  int tid = threadIdx.x;
  __shared__ float rows[16][FD];
  __shared__ float red[3][2][128];
  for (int i = tid; i < 16 * FD; i += 256) {
    int r = i / FD, c = i - r * FD;
    rows[r][c] = feats[(size_t)(b * N + n0 + r) * FD + c];
  }
  __syncthreads();
  int o = tid & 127, g = tid >> 7;
  float acc[8] = {};
  for (int c = 0; c < FD; c += 4) {
    float w0 = Wht[(c + 0) * 128 + o];
    float w1 = Wht[(c + 1) * 128 + o];
    float w2 = Wht[(c + 2) * 128 + o];
    float w3 = Wht[(c + 3) * 128 + o];
#pragma unroll
    for (int j = 0; j < 8; ++j) {
      float4 r4 = *reinterpret_cast<const float4*>(&rows[g * 8 + j][c]);
      acc[j] += w0 * r4.x + w1 * r4.y + w2 * r4.z + w3 * r4.w;
    }
  }
  float s = 0.f, ss = 0.f, mx = -3.4e38f;
#pragma unroll
  for (int j = 0; j < 8; ++j) {
    float f = acc[j];
    s += f;
    ss += f * f;
    mx = fmaxf(mx, f);
  }
  red[0][g][o] = s;
  red[1][g][o] = ss;
  red[2][g][o] = mx;
  __syncthreads();
  if (g == 0) {
    s += red[0][1][o];
    ss += red[1][1][o];
    mx = fmaxf(mx, red[2][1][o]);
    atomicAdd(&fsum[b * 128 + o], s);
    atomicAdd(&fss[b * 128 + o], ss);
    unsigned u = __float_as_uint(mx);
    u = (u & 0x80000000u) ? ~u : (u | 0x80000000u);
    atomicMax(&fmaxu[b * 128 + o], u);
  }
}

// ---------------------------------------------------------------- head
__global__ __launch_bounds__(128) void head_kernel(const float* __restrict__ fsum,
                                                   const float* __restrict__ fss,
                                                   const unsigned* __restrict__ fmaxu,
                                                   const float* __restrict__ fc1w,
                                                   const float* __restrict__ fc1b,
                                                   const float* __restrict__ fc2w,
                                                   const float* __restrict__ fc2b,
                                                   void* __restrict__ out,
                                                   const int* __restrict__ flag) {
  int b = blockIdx.x, o = threadIdx.x;
  __shared__ float gs[128], t1[128], ys[128];
  constexpr float invN = 1.f / N;
  float m = fsum[b * 128 + o] * invN;
  float v = fmaxf(fss[b * 128 + o] * invN - m * m, 0.f);
  unsigned u = fmaxu[b * 128 + o];
  unsigned bits = (u & 0x80000000u) ? (u ^ 0x80000000u) : ~u;
  float fx = __uint_as_float(bits);
  gs[o] = lrelu((fx - m) * rsqrtf(v + EPS));
  __syncthreads();
  float a = fc1b[o];
  for (int c = 0; c < 128; ++c) a += fc1w[o * 128 + c] * gs[c];
  t1[o] = a;
  __syncthreads();
  float mm = 0.f;
  for (int c = 0; c < 128; ++c) mm += t1[c];
  mm *= (1.f / 128);
  float vv = 0.f;
  for (int c = 0; c < 128; ++c) {
    float d = t1[c] - mm;
    vv += d * d;
  }
  vv *= (1.f / 128);
  ys[o] = lrelu((a - mm) * rsqrtf(vv + EPS));
  __syncthreads();
  float r = fc2b[o];
  for (int c = 0; c < 128; ++c) r += fc2w[o * 128 + c] * ys[c];
  if (flag[0])
    ((float*)out)[b * 128 + o] = r;
  else
    ((bf16*)out)[b * 128 + o] = __float2bfloat16(r);
}

// ---------------------------------------------------------------- driver
template <int C, int O>
static void run_layer(const float* h, int hstride, float* featdst, const float* Wp,
                      float* cstats, float* dist, float* projb, int* idxb,
                      hipStream_t stream) {
  constexpr int NSEL = B * N / 4;
  constexpr int NPROJ = (2 * O / 64) * (B * N / 64);
  dist_kernel<C><<<dim3(N / 128, N / 128, B), 256, 0, stream>>>(h, hstride, dist);
  selproj_kernel<C, 2 * O><<<NSEL + NPROJ, 256, 0, stream>>>(dist, idxb, h, hstride, Wp,
                                                             projb);
  edge_reduce_kernel<O><<<B * N / 4, 256, 0, stream>>>(projb, idxb, cstats, featdst);
  finalize_kernel<<<B * N * O / 256, 256, 0, stream>>>(cstats, featdst, O);
}

extern "C" void kernel_launch(void* const* d_in, const int* in_sizes, int n_in,
                              void* d_out, int out_size, void* d_ws, size_t ws_size,
                              hipStream_t stream) {
  float* ws = (float*)d_ws;
  float* xf = ws + O_XF;
  float* feats = ws + O_FEATS;
  float* dist = ws + O_DIST;
  float* projb = ws + O_PROJ;
  int* idxb = (int*)(ws + O_IDX);
  int* flag = (int*)(ws + O_FLAG);

  prep_kernel<<<(PREP_TOTAL + 255) / 256, 256, 0, stream>>>(
      d_in[0], d_in[2], d_in[3], d_in[4], d_in[5], d_in[6], d_in[7], d_in[8], d_in[9],
      d_in[10], ws);

  run_layer<3, 32>(xf, 3, feats + 0, ws + O_WP0, ws + O_CS0, dist, projb, idxb, stream);
  run_layer<32, 64>(feats + 0, FD, feats + 32, ws + O_WP1, ws + O_CS1, dist, projb, idxb,
                    stream);
  run_layer<64, 128>(feats + 32, FD, feats + 96, ws + O_WP2, ws + O_CS2, dist, projb, idxb,
                     stream);
  run_layer<128, 256>(feats + 96, FD, feats + 224, ws + O_WP3, ws + O_CS3, dist, projb,
                      idxb, stream);

  fstage_kernel<<<B * 128, 256, 0, stream>>>(feats, ws + O_WHT, ws + O_FSUM, ws + O_FSS,
                                             (unsigned*)(ws + O_FMAX));
  head_kernel<<<B, 128, 0, stream>>>(ws + O_FSUM, ws + O_FSS, (unsigned*)(ws + O_FMAX),
                                     ws + O_F1W, ws + O_F1B, ws + O_F2W, ws + O_F2B, d_out,
                                     flag);
}

// Round 3
// 865.355 us; speedup vs baseline: 1.1415x; 1.1415x over previous
//
#include <hip/hip_runtime.h>
#include <hip/hip_bf16.h>
#include <cstdint>

using bf16 = __hip_bfloat16;

static constexpr int B = 2;
static constexpr int N = 2048;
static constexpr int KNN = 32;
static constexpr int FD = 480;
static constexpr float EPS = 1e-5f;
static constexpr float SLOPE = 0.2f;
static constexpr int REP = 8;  // cstats atomic replicas (contention spreading)

// ---------------- workspace layout (floats), all compile-time ----------------
static constexpr size_t N_XF = (size_t)B * N * 3;
static constexpr size_t N_FEATS = (size_t)B * N * FD;
static constexpr size_t N_DIST = (size_t)B * N * N;
static constexpr size_t N_IDX = (size_t)B * N * KNN;
static constexpr size_t N_PROJ = (size_t)B * N * 512;  // proj [BN][2O], O<=256
static constexpr size_t O_XF = 0;
static constexpr size_t O_FEATS = O_XF + N_XF;
static constexpr size_t O_DIST = O_FEATS + N_FEATS;
static constexpr size_t O_IDX = O_DIST + N_DIST;
static constexpr size_t O_PROJ = O_IDX + N_IDX;
static constexpr size_t O_WP0 = O_PROJ + N_PROJ;      // [3][64]
static constexpr size_t O_WP1 = O_WP0 + 192;          // [32][128]
static constexpr size_t O_WP2 = O_WP1 + 4096;         // [64][256]
static constexpr size_t O_WP3 = O_WP2 + 16384;        // [128][512]
static constexpr size_t O_WHT = O_WP3 + 65536;
static constexpr size_t O_F1W = O_WHT + 61440;
static constexpr size_t O_F1B = O_F1W + 16384;
static constexpr size_t O_F2W = O_F1B + 128;
static constexpr size_t O_F2B = O_F2W + 16384;
static constexpr size_t O_FLAG = O_F2B + 128;
static constexpr size_t O_CS0 = O_FLAG + 16;   // zero region starts here
// cstats per layer: REP * B * O * 2 floats
static constexpr size_t O_CS1 = O_CS0 + (size_t)REP * B * 32 * 2;    // +1024
static constexpr size_t O_CS2 = O_CS1 + (size_t)REP * B * 64 * 2;    // +2048
static constexpr size_t O_CS3 = O_CS2 + (size_t)REP * B * 128 * 2;   // +4096
static constexpr size_t O_FSUM = O_CS3 + (size_t)REP * B * 256 * 2;  // +8192
static constexpr size_t O_FSS = O_FSUM + 256;
static constexpr size_t O_FMAX = O_FSS + 256;
static constexpr size_t O_END = O_FMAX + 256;
static constexpr size_t N_ZERO = O_END - O_CS0;

__device__ __forceinline__ float lrelu(float x) { return x >= 0.f ? x : SLOPE * x; }

__device__ __forceinline__ float load_in(const void* p, int i, int isf32) {
  return isf32 ? ((const float*)p)[i] : __bfloat162float(((const bf16*)p)[i]);
}

// ---------------------------------------------------------------- prep (fused)
static constexpr int PREP_TOTAL =
    (int)(N_XF + 96 + 2048 + 8192 + 32768 + 61440 + 16384 + 128 + 16384 + 128 + N_ZERO);

__global__ __launch_bounds__(256) void prep_kernel(
    const void* __restrict__ x, const void* __restrict__ W0, const void* __restrict__ W1,
    const void* __restrict__ W2, const void* __restrict__ W3, const void* __restrict__ Wh,
    const void* __restrict__ fc1w, const void* __restrict__ fc1b,
    const void* __restrict__ fc2w, const void* __restrict__ fc2b, float* __restrict__ ws) {
  __shared__ float red[256];
  const unsigned short* xr = (const unsigned short*)x;
  float mx = 0.f;
  for (int i = threadIdx.x; i < B * N * 3; i += 256) {
    float v = __uint_as_float(((unsigned)xr[i]) << 16);
    v = fabsf(v);
    if (!(v < 1e30f)) v = 1e30f;  // NaN/inf -> huge
    mx = fmaxf(mx, v);
  }
  red[threadIdx.x] = mx;
  __syncthreads();
  for (int s = 128; s > 0; s >>= 1) {
    if (threadIdx.x < s) red[threadIdx.x] = fmaxf(red[threadIdx.x], red[threadIdx.x + s]);
    __syncthreads();
  }
  int isf = red[0] > 1e3f ? 1 : 0;
  if (blockIdx.x == 0 && threadIdx.x == 0) ((int*)(ws + O_FLAG))[0] = isf;

  int idx = blockIdx.x * 256 + threadIdx.x;
  if (idx < (int)N_XF) { ws[O_XF + idx] = load_in(x, idx, isf); return; }
  idx -= (int)N_XF;
  if (idx < 96) {  // W0: O=32,C=3
    int o = idx / 3, c = idx - o * 3;
    float a = load_in(W0, o * 6 + c, isf);
    float bb = load_in(W0, o * 6 + 3 + c, isf);
    ws[O_WP0 + c * 64 + o] = a;
    ws[O_WP0 + c * 64 + 32 + o] = bb - a;
    return;
  }
  idx -= 96;
  if (idx < 2048) {  // W1: O=64,C=32
    int o = idx >> 5, c = idx & 31;
    float a = load_in(W1, o * 64 + c, isf);
    float bb = load_in(W1, o * 64 + 32 + c, isf);
    ws[O_WP1 + c * 128 + o] = a;
    ws[O_WP1 + c * 128 + 64 + o] = bb - a;
    return;
  }
  idx -= 2048;
  if (idx < 8192) {  // W2: O=128,C=64
    int o = idx >> 6, c = idx & 63;
    float a = load_in(W2, o * 128 + c, isf);
    float bb = load_in(W2, o * 128 + 64 + c, isf);
    ws[O_WP2 + c * 256 + o] = a;
    ws[O_WP2 + c * 256 + 128 + o] = bb - a;
    return;
  }
  idx -= 8192;
  if (idx < 32768) {  // W3: O=256,C=128
    int o = idx >> 7, c = idx & 127;
    float a = load_in(W3, o * 256 + c, isf);
    float bb = load_in(W3, o * 256 + 128 + c, isf);
    ws[O_WP3 + c * 512 + o] = a;
    ws[O_WP3 + c * 512 + 256 + o] = bb - a;
    return;
  }
  idx -= 32768;
  if (idx < 61440) {  // Wh [128][480] -> [480][128]
    int o = idx / 480, c = idx - o * 480;
    ws[O_WHT + c * 128 + o] = load_in(Wh, idx, isf);
    return;
  }
  idx -= 61440;
  if (idx < 16384) { ws[O_F1W + idx] = load_in(fc1w, idx, isf); return; }
  idx -= 16384;
  if (idx < 128) { ws[O_F1B + idx] = load_in(fc1b, idx, isf); return; }
  idx -= 128;
  if (idx < 16384) { ws[O_F2W + idx] = load_in(fc2w, idx, isf); return; }
  idx -= 16384;
  if (idx < 128) { ws[O_F2B + idx] = load_in(fc2b, idx, isf); return; }
  idx -= 128;
  if (idx < (int)N_ZERO) ws[O_CS0 + idx] = 0.f;
}

// ---------------------------------------------------------------- dist (sq fused)
template <int C>
__global__ __launch_bounds__(256) void dist_kernel(const float* __restrict__ h, int hstride,
                                                   float* __restrict__ dist) {
  constexpr int CW = 16;
  __shared__ float Ast[CW][132];
  __shared__ float Bst[CW][132];
  __shared__ float sqn[128], sqm[128];
  int b = blockIdx.z;
  int n0 = blockIdx.y * 128, m0 = blockIdx.x * 128;
  int tid = threadIdx.x;
  int tx = tid & 15, ty = tid >> 4;
  int rr = tid & 127;
  float dot[8][8] = {};
  float sqacc = 0.f;
  for (int cc = 0; cc < C; cc += CW) {
    for (int i = tid; i < 128 * CW; i += 256) {
      int c = i & 15, r = i >> 4;
      int gc = cc + c;
      float av = 0.f, bv = 0.f;
      if (gc < C) {
        av = h[(size_t)(b * N + n0 + r) * hstride + gc];
        bv = h[(size_t)(b * N + m0 + r) * hstride + gc];
      }
      Ast[c][r] = av;
      Bst[c][r] = bv;
    }
    __syncthreads();
    if (tid < 128) {
#pragma unroll
      for (int c = 0; c < CW; ++c) { float v = Ast[c][rr]; sqacc += v * v; }
    } else {
#pragma unroll
      for (int c = 0; c < CW; ++c) { float v = Bst[c][rr]; sqacc += v * v; }
    }
#pragma unroll
    for (int c = 0; c < CW; ++c) {
      float4 a0 = *reinterpret_cast<const float4*>(&Ast[c][ty * 8]);
      float4 a1 = *reinterpret_cast<const float4*>(&Ast[c][ty * 8 + 4]);
      float4 b0 = *reinterpret_cast<const float4*>(&Bst[c][tx * 4]);
      float4 b1 = *reinterpret_cast<const float4*>(&Bst[c][64 + tx * 4]);
      float av[8] = {a0.x, a0.y, a0.z, a0.w, a1.x, a1.y, a1.z, a1.w};
      float bv[8] = {b0.x, b0.y, b0.z, b0.w, b1.x, b1.y, b1.z, b1.w};
#pragma unroll
      for (int i = 0; i < 8; ++i)
#pragma unroll
        for (int j = 0; j < 8; ++j) dot[i][j] += av[i] * bv[j];
    }
    __syncthreads();
  }
  if (tid < 128) sqn[rr] = sqacc; else sqm[rr] = sqacc;
  __syncthreads();
#pragma unroll
  for (int i = 0; i < 8; ++i) {
    int nn = n0 + ty * 8 + i;
    float sn = sqn[ty * 8 + i];
    float4 w;
    w.x = sn + sqm[tx * 4 + 0] - 2.f * dot[i][0];
    w.y = sn + sqm[tx * 4 + 1] - 2.f * dot[i][1];
    w.z = sn + sqm[tx * 4 + 2] - 2.f * dot[i][2];
    w.w = sn + sqm[tx * 4 + 3] - 2.f * dot[i][3];
    *reinterpret_cast<float4*>(&dist[(size_t)(b * N + nn) * N + m0 + tx * 4]) = w;
    float4 w2;
    w2.x = sn + sqm[64 + tx * 4 + 0] - 2.f * dot[i][4];
    w2.y = sn + sqm[64 + tx * 4 + 1] - 2.f * dot[i][5];
    w2.z = sn + sqm[64 + tx * 4 + 2] - 2.f * dot[i][6];
    w2.w = sn + sqm[64 + tx * 4 + 3] - 2.f * dot[i][7];
    *reinterpret_cast<float4*>(&dist[(size_t)(b * N + nn) * N + m0 + 64 + tx * 4]) = w2;
  }
}

__device__ __forceinline__ unsigned long long wave_min_u64(unsigned long long v) {
#pragma unroll
  for (int m = 1; m < 64; m <<= 1) {
    unsigned lo = (unsigned)v;
    unsigned hi = (unsigned)(v >> 32);
    unsigned olo = (unsigned)__shfl_xor((int)lo, m, 64);
    unsigned ohi = (unsigned)__shfl_xor((int)hi, m, 64);
    unsigned long long ov = ((unsigned long long)ohi << 32) | olo;
    if (ov < v) v = ov;
  }
  return v;
}

#define ARGMIN32(dk, ld, lj)                                        \
  {                                                                 \
    unsigned kv0 = dk[0], kv1 = dk[8], kv2 = dk[16], kv3 = dk[24];  \
    int j0 = 0, j1 = 8, j2 = 16, j3 = 24;                           \
    _Pragma("unroll")                                               \
    for (int t = 1; t < 8; ++t) {                                   \
      if (dk[t] < kv0) { kv0 = dk[t]; j0 = t; }                     \
      if (dk[8 + t] < kv1) { kv1 = dk[8 + t]; j1 = 8 + t; }         \
      if (dk[16 + t] < kv2) { kv2 = dk[16 + t]; j2 = 16 + t; }      \
      if (dk[24 + t] < kv3) { kv3 = dk[24 + t]; j3 = 24 + t; }      \
    }                                                               \
    if (kv1 < kv0) { kv0 = kv1; j0 = j1; }                          \
    if (kv3 < kv2) { kv2 = kv3; j2 = j3; }                          \
    if (kv2 < kv0) { kv0 = kv2; j0 = j2; }                          \
    ld = kv0; lj = j0;                                              \
  }

// ---------------------------------------------------------------- fused select || proj
template <int C, int NO2>
__global__ __launch_bounds__(256) void selproj_kernel(const float* __restrict__ dist,
                                                      int* __restrict__ idxb,
                                                      const float* __restrict__ h,
                                                      int hstride,
                                                      const float* __restrict__ Wp,
                                                      float* __restrict__ projb) {
  constexpr int NSEL = B * N / 4;
  constexpr int MT = NO2 / 64;
  constexpr int CW = 16;
  __shared__ float As[64][17];
  __shared__ float Bs[64][17];
  if (blockIdx.x < NSEL) {
    int row = blockIdx.x * 4 + (threadIdx.x >> 6);  // b*N + n
    int lane = threadIdx.x & 63;
    const float* drow = dist + (size_t)row * N;
    unsigned dk[32];
#pragma unroll
    for (int j = 0; j < 32; ++j) {
      unsigned u = __float_as_uint(drow[j * 64 + lane]);
      dk[j] = (u & 0x80000000u) ? ~u : (u | 0x80000000u);
    }
    unsigned ld;
    int lj;
    ARGMIN32(dk, ld, lj);
    unsigned saved = 0;
    for (int it = 0; it <= KNN; ++it) {
      unsigned long long lkey =
          ((unsigned long long)ld << 32) | (unsigned)(lj * 64 + lane);
      unsigned long long g = wave_min_u64(lkey);
      if (it > 0 && lane == it - 1) saved = (unsigned)(g & 0xFFFFFFFFull);
      if (lkey == g) {  // unique m per lane -> exactly one winner
#pragma unroll
        for (int j = 0; j < 32; ++j)
          if (j == lj) dk[j] = 0xFFFFFFFFu;
        ARGMIN32(dk, ld, lj);
      }
    }
    if (lane < KNN) idxb[row * KNN + lane] = (int)saved;
  } else {
    int tile = blockIdx.x - NSEL;
    int m0 = (tile % MT) * 64;
    int n0 = (tile / MT) * 64;
    int tid = threadIdx.x;
    int tx = tid & 15, ty = tid >> 4;
    float dot[4][4] = {};
    for (int cc = 0; cc < C; cc += CW) {
      for (int i = tid; i < 64 * CW; i += 256) {
        int r = i >> 4, c = i & 15;
        int gc = cc + c;
        As[r][c] = (gc < C) ? h[(size_t)(n0 + r) * hstride + gc] : 0.f;
      }
      for (int i = tid; i < 64 * CW; i += 256) {
        int c = i >> 6, m = i & 63;
        int gc = cc + c;
        Bs[m][c] = (gc < C) ? Wp[(size_t)gc * NO2 + m0 + m] : 0.f;
      }
      __syncthreads();
#pragma unroll
      for (int c = 0; c < CW; ++c) {
        float av[4], bv[4];
#pragma unroll
        for (int i = 0; i < 4; ++i) av[i] = As[ty * 4 + i][c];
#pragma unroll
        for (int j = 0; j < 4; ++j) bv[j] = Bs[tx * 4 + j][c];
#pragma unroll
        for (int i = 0; i < 4; ++i)
#pragma unroll
          for (int j = 0; j < 4; ++j) dot[i][j] += av[i] * bv[j];
      }
      __syncthreads();
    }
#pragma unroll
    for (int i = 0; i < 4; ++i) {
      float4 w;
      w.x = dot[i][0];
      w.y = dot[i][1];
      w.z = dot[i][2];
      w.w = dot[i][3];
      *reinterpret_cast<float4*>(&projb[(size_t)(n0 + ty * 4 + i) * NO2 + m0 + tx * 4]) = w;
    }
  }
}

// ---------------------------------------------------------------- edge reduce
// R16: one block per point, 256 threads = TG k-groups x Q quads. KS<=8 gathers
// per thread (<=32 VGPRs in flight -> compiler keeps them pipelined; R15's
// KS=32 with VGPR budget 56 silently serialized the loads). Grid B*N = 4096
// blocks -> 16 blocks/CU -> real TLP (R15: 1024 blocks, 12% occupancy, 1
// wave/SIMD, zero TLP -> every gather paid full latency serially).
// Cross-k reduce: shfl_xor butterfly over group bits, then LDS across waves.
// cstats atomics spread over REP replicas (rep = bn&7) to cut same-address
// serialization; finalize folds replicas.
template <int O>
__global__ __launch_bounds__(256) void edge_reduce_kernel(const float* __restrict__ proj,
                                                          const int* __restrict__ idxb,
                                                          float* __restrict__ cstats,
                                                          float* __restrict__ featdst) {
  constexpr int Q = O / 4;        // float4 quads per half-row (8..64)
  constexpr int TG = 256 / Q;     // k-groups per block (32..4)
  constexpr int KS = KNN / TG;    // neighbors per thread (1..8)
  constexpr int G = 64 / Q;       // k-groups per wave (8..1)
  constexpr int NW = 4;           // waves per block
  constexpr int NO2 = 2 * O;
  __shared__ int knn[KNN];
  __shared__ float4 red[3][NW][Q];
  int bn = blockIdx.x;
  int b = bn >> 11;
  int tid = threadIdx.x;
  int w = tid >> 6;
  int lane = tid & 63;
  int g = lane / Q;
  int q = lane - g * Q;
  int kg = w * G + g;  // global k-group 0..TG-1
  if (tid < KNN) knn[tid] = idxb[bn * KNN + tid];
  __syncthreads();
  int jbase = b << 11;  // knn indices are within-batch; proj rows are global bn
  const float4 h0 = *reinterpret_cast<const float4*>(&proj[(size_t)bn * NO2 + O + q * 4]);
  float4 mx = {-3.4e38f, -3.4e38f, -3.4e38f, -3.4e38f};
  float4 s = {0.f, 0.f, 0.f, 0.f}, ss = {0.f, 0.f, 0.f, 0.f};

  float4 v[KS];
#pragma unroll
  for (int t = 0; t < KS; ++t) {
    int j = jbase + knn[kg * KS + t];
    v[t] = *reinterpret_cast<const float4*>(&proj[(size_t)j * NO2 + q * 4]);
  }
#pragma unroll
  for (int t = 0; t < KS; ++t) {
    float ex = v[t].x + h0.x, ey = v[t].y + h0.y, ez = v[t].z + h0.z, ew = v[t].w + h0.w;
    s.x += ex; ss.x += ex * ex; mx.x = fmaxf(mx.x, ex);
    s.y += ey; ss.y += ey * ey; mx.y = fmaxf(mx.y, ey);
    s.z += ez; ss.z += ez * ez; mx.z = fmaxf(mx.z, ez);
    s.w += ew; ss.w += ew * ew; mx.w = fmaxf(mx.w, ew);
  }

  if constexpr (G > 1) {
#pragma unroll
    for (int m = Q; m < 64; m <<= 1) {
      mx.x = fmaxf(mx.x, __shfl_xor(mx.x, m, 64));
      mx.y = fmaxf(mx.y, __shfl_xor(mx.y, m, 64));
      mx.z = fmaxf(mx.z, __shfl_xor(mx.z, m, 64));
      mx.w = fmaxf(mx.w, __shfl_xor(mx.w, m, 64));
      s.x += __shfl_xor(s.x, m, 64);
      s.y += __shfl_xor(s.y, m, 64);
      s.z += __shfl_xor(s.z, m, 64);
      s.w += __shfl_xor(s.w, m, 64);
      ss.x += __shfl_xor(ss.x, m, 64);
      ss.y += __shfl_xor(ss.y, m, 64);
      ss.z += __shfl_xor(ss.z, m, 64);
      ss.w += __shfl_xor(ss.w, m, 64);
    }
  }
  if (lane < Q) {
    red[0][w][q] = mx;
    red[1][w][q] = s;
    red[2][w][q] = ss;
  }
  __syncthreads();
  if (tid < Q) {
    float4 M = red[0][0][tid], S = red[1][0][tid], SS = red[2][0][tid];
#pragma unroll
    for (int r = 1; r < NW; ++r) {
      float4 a = red[0][r][tid], c0 = red[1][r][tid], c1 = red[2][r][tid];
      M.x = fmaxf(M.x, a.x); M.y = fmaxf(M.y, a.y);
      M.z = fmaxf(M.z, a.z); M.w = fmaxf(M.w, a.w);
      S.x += c0.x; S.y += c0.y; S.z += c0.z; S.w += c0.w;
      SS.x += c1.x; SS.y += c1.y; SS.z += c1.z; SS.w += c1.w;
    }
    *reinterpret_cast<float4*>(&featdst[(size_t)bn * FD + tid * 4]) = M;
    int rep = bn & (REP - 1);
    float* cs = cstats + (size_t)rep * (B * O * 2) + (size_t)(b * O + tid * 4) * 2;
    atomicAdd(&cs[0], S.x);
    atomicAdd(&cs[1], SS.x);
    atomicAdd(&cs[2], S.y);
    atomicAdd(&cs[3], SS.y);
    atomicAdd(&cs[4], S.z);
    atomicAdd(&cs[5], SS.z);
    atomicAdd(&cs[6], S.w);
    atomicAdd(&cs[7], SS.w);
  }
}

// in-place: featdst = lrelu((featdst - mean) * rsqrt(var + eps)); folds REP replicas
__global__ void finalize_kernel(const float* __restrict__ cstats,
                                float* __restrict__ featdst, int O) {
  int i = blockIdx.x * 256 + threadIdx.x;
  int o = i % O;
  int bn = i / O;
  int b = bn >> 11;
  float s = 0.f, ss = 0.f;
#pragma unroll
  for (int r = 0; r < REP; ++r) {
    s += cstats[(size_t)r * (B * O * 2) + (size_t)(b * O + o) * 2 + 0];
    ss += cstats[(size_t)r * (B * O * 2) + (size_t)(b * O + o) * 2 + 1];
  }
  constexpr float inv = 1.f / ((float)N * KNN);
  float m = s * inv;
  float v = fmaxf(ss * inv - m * m, 0.f);
  float* p = &featdst[(size_t)bn * FD + o];
  float e = (*p - m) * rsqrtf(v + EPS);
  *p = lrelu(e);
}

// ---------------------------------------------------------------- 480 -> 128 stage
__global__ __launch_bounds__(256) void fstage_kernel(const float* __restrict__ feats,
                                                     const float* __restrict__ Wht,
                                                     float* __restrict__ fsum,
                                                     float* __restrict__ fss,
                                                     unsigned* __restrict__ fmaxu) {
  int blk = blockIdx.x;
  int b = blk >> 7;
  int n0 = (blk & 127) * 16;
  int tid = threadIdx.x;
  __shared__ float rows[16][FD];
  __shared__ float red[3][2][128];
  for (int i = tid; i < 16 * FD; i += 256) {
    int r = i / FD, c = i - r * FD;
    rows[r][c] = feats[(size_t)(b * N + n0 + r) * FD + c];
  }
  __syncthreads();
  int o = tid & 127, g = tid >> 7;
  float acc[8] = {};
  for (int c = 0; c < FD; c += 4) {
    float w0 = Wht[(c + 0) * 128 + o];
    float w1 = Wht[(c + 1) * 128 + o];
    float w2 = Wht[(c + 2) * 128 + o];
    float w3 = Wht[(c + 3) * 128 + o];
#pragma unroll
    for (int j = 0; j < 8; ++j) {
      float4 r4 = *reinterpret_cast<const float4*>(&rows[g * 8 + j][c]);
      acc[j] += w0 * r4.x + w1 * r4.y + w2 * r4.z + w3 * r4.w;
    }
  }
  float s = 0.f, ss = 0.f, mx = -3.4e38f;
#pragma unroll
  for (int j = 0; j < 8; ++j) {
    float f = acc[j];
    s += f;
    ss += f * f;
    mx = fmaxf(mx, f);
  }
  red[0][g][o] = s;
  red[1][g][o] = ss;
  red[2][g][o] = mx;
  __syncthreads();
  if (g == 0) {
    s += red[0][1][o];
    ss += red[1][1][o];
    mx = fmaxf(mx, red[2][1][o]);
    atomicAdd(&fsum[b * 128 + o], s);
    atomicAdd(&fss[b * 128 + o], ss);
    unsigned u = __float_as_uint(mx);
    u = (u & 0x80000000u) ? ~u : (u | 0x80000000u);
    atomicMax(&fmaxu[b * 128 + o], u);
  }
}

// ---------------------------------------------------------------- head
__global__ __launch_bounds__(128) void head_kernel(const float* __restrict__ fsum,
                                                   const float* __restrict__ fss,
                                                   const unsigned* __restrict__ fmaxu,
                                                   const float* __restrict__ fc1w,
                                                   const float* __restrict__ fc1b,
                                                   const float* __restrict__ fc2w,
                                                   const float* __restrict__ fc2b,
                                                   void* __restrict__ out,
                                                   const int* __restrict__ flag) {
  int b = blockIdx.x, o = threadIdx.x;
  __shared__ float gs[128], t1[128], ys[128];
  constexpr float invN = 1.f / N;
  float m = fsum[b * 128 + o] * invN;
  float v = fmaxf(fss[b * 128 + o] * invN - m * m, 0.f);
  unsigned u = fmaxu[b * 128 + o];
  unsigned bits = (u & 0x80000000u) ? (u ^ 0x80000000u) : ~u;
  float fx = __uint_as_float(bits);
  gs[o] = lrelu((fx - m) * rsqrtf(v + EPS));
  __syncthreads();
  float a = fc1b[o];
  for (int c = 0; c < 128; ++c) a += fc1w[o * 128 + c] * gs[c];
  t1[o] = a;
  __syncthreads();
  float mm = 0.f;
  for (int c = 0; c < 128; ++c) mm += t1[c];
  mm *= (1.f / 128);
  float vv = 0.f;
  for (int c = 0; c < 128; ++c) {
    float d = t1[c] - mm;
    vv += d * d;
  }
  vv *= (1.f / 128);
  ys[o] = lrelu((a - mm) * rsqrtf(vv + EPS));
  __syncthreads();
  float r = fc2b[o];
  for (int c = 0; c < 128; ++c) r += fc2w[o * 128 + c] * ys[c];
  if (flag[0])
    ((float*)out)[b * 128 + o] = r;
  else
    ((bf16*)out)[b * 128 + o] = __float2bfloat16(r);
}

// ---------------------------------------------------------------- driver
template <int C, int O>
static void run_layer(const float* h, int hstride, float* featdst, const float* Wp,
                      float* cstats, float* dist, float* projb, int* idxb,
                      hipStream_t stream) {
  constexpr int NSEL = B * N / 4;
  constexpr int NPROJ = (2 * O / 64) * (B * N / 64);
  dist_kernel<C><<<dim3(N / 128, N / 128, B), 256, 0, stream>>>(h, hstride, dist);
  selproj_kernel<C, 2 * O><<<NSEL + NPROJ, 256, 0, stream>>>(dist, idxb, h, hstride, Wp,
                                                             projb);
  edge_reduce_kernel<O><<<B * N, 256, 0, stream>>>(projb, idxb, cstats, featdst);
  finalize_kernel<<<B * N * O / 256, 256, 0, stream>>>(cstats, featdst, O);
}

extern "C" void kernel_launch(void* const* d_in, const int* in_sizes, int n_in,
                              void* d_out, int out_size, void* d_ws, size_t ws_size,
                              hipStream_t stream) {
  float* ws = (float*)d_ws;
  float* xf = ws + O_XF;
  float* feats = ws + O_FEATS;
  float* dist = ws + O_DIST;
  float* projb = ws + O_PROJ;
  int* idxb = (int*)(ws + O_IDX);
  int* flag = (int*)(ws + O_FLAG);

  prep_kernel<<<(PREP_TOTAL + 255) / 256, 256, 0, stream>>>(
      d_in[0], d_in[2], d_in[3], d_in[4], d_in[5], d_in[6], d_in[7], d_in[8], d_in[9],
      d_in[10], ws);

  run_layer<3, 32>(xf, 3, feats + 0, ws + O_WP0, ws + O_CS0, dist, projb, idxb, stream);
  run_layer<32, 64>(feats + 0, FD, feats + 32, ws + O_WP1, ws + O_CS1, dist, projb, idxb,
                    stream);
  run_layer<64, 128>(feats + 32, FD, feats + 96, ws + O_WP2, ws + O_CS2, dist, projb, idxb,
                     stream);
  run_layer<128, 256>(feats + 96, FD, feats + 224, ws + O_WP3, ws + O_CS3, dist, projb,
                      idxb, stream);

  fstage_kernel<<<B * 128, 256, 0, stream>>>(feats, ws + O_WHT, ws + O_FSUM, ws + O_FSS,
                                             (unsigned*)(ws + O_FMAX));
  head_kernel<<<B, 128, 0, stream>>>(ws + O_FSUM, ws + O_FSS, (unsigned*)(ws + O_FMAX),
                                     ws + O_F1W, ws + O_F1B, ws + O_F2W, ws + O_F2B, d_out,
                                     flag);
}

// Round 4
// 693.645 us; speedup vs baseline: 1.4240x; 1.2475x over previous
//
#include <hip/hip_runtime.h>
#include <hip/hip_bf16.h>
#include <cstdint>

using bf16 = __hip_bfloat16;

static constexpr int B = 2;
static constexpr int N = 2048;
static constexpr int KNN = 32;
static constexpr int FD = 480;
static constexpr float EPS = 1e-5f;
static constexpr float SLOPE = 0.2f;
static constexpr int REP = 8;  // cstats atomic replicas (contention spreading)

// ---------------- workspace layout (floats), all compile-time ----------------
static constexpr size_t N_XF = (size_t)B * N * 3;
static constexpr size_t N_FEATS = (size_t)B * N * FD;
static constexpr size_t N_DIST = (size_t)B * N * N;
static constexpr size_t N_IDX = (size_t)B * N * KNN;
static constexpr size_t N_PROJ = (size_t)B * N * 512;  // proj [BN][2O] or slab-major
static constexpr size_t O_XF = 0;
static constexpr size_t O_FEATS = O_XF + N_XF;
static constexpr size_t O_DIST = O_FEATS + N_FEATS;
static constexpr size_t O_IDX = O_DIST + N_DIST;
static constexpr size_t O_PROJ = O_IDX + N_IDX;
static constexpr size_t O_WP0 = O_PROJ + N_PROJ;      // [3][64]
static constexpr size_t O_WP1 = O_WP0 + 192;          // [32][128]
static constexpr size_t O_WP2 = O_WP1 + 4096;         // [64][256]
static constexpr size_t O_WP3 = O_WP2 + 16384;        // [128][512]
static constexpr size_t O_WHT = O_WP3 + 65536;
static constexpr size_t O_F1W = O_WHT + 61440;
static constexpr size_t O_F1B = O_F1W + 16384;
static constexpr size_t O_F2W = O_F1B + 128;
static constexpr size_t O_F2B = O_F2W + 16384;
static constexpr size_t O_FLAG = O_F2B + 128;
static constexpr size_t O_CS0 = O_FLAG + 16;   // zero region starts here
// cstats per layer: REP * B * O * 2 floats
static constexpr size_t O_CS1 = O_CS0 + (size_t)REP * B * 32 * 2;    // +1024
static constexpr size_t O_CS2 = O_CS1 + (size_t)REP * B * 64 * 2;    // +2048
static constexpr size_t O_CS3 = O_CS2 + (size_t)REP * B * 128 * 2;   // +4096
static constexpr size_t O_FSUM = O_CS3 + (size_t)REP * B * 256 * 2;  // +8192
static constexpr size_t O_FSS = O_FSUM + 256;
static constexpr size_t O_FMAX = O_FSS + 256;
static constexpr size_t O_END = O_FMAX + 256;
static constexpr size_t N_ZERO = O_END - O_CS0;

__device__ __forceinline__ float lrelu(float x) { return x >= 0.f ? x : SLOPE * x; }

__device__ __forceinline__ float load_in(const void* p, int i, int isf32) {
  return isf32 ? ((const float*)p)[i] : __bfloat162float(((const bf16*)p)[i]);
}

// ---------------------------------------------------------------- prep (fused)
static constexpr int PREP_TOTAL =
    (int)(N_XF + 96 + 2048 + 8192 + 32768 + 61440 + 16384 + 128 + 16384 + 128 + N_ZERO);

__global__ __launch_bounds__(256) void prep_kernel(
    const void* __restrict__ x, const void* __restrict__ W0, const void* __restrict__ W1,
    const void* __restrict__ W2, const void* __restrict__ W3, const void* __restrict__ Wh,
    const void* __restrict__ fc1w, const void* __restrict__ fc1b,
    const void* __restrict__ fc2w, const void* __restrict__ fc2b, float* __restrict__ ws) {
  __shared__ float red[256];
  const unsigned short* xr = (const unsigned short*)x;
  float mx = 0.f;
  for (int i = threadIdx.x; i < B * N * 3; i += 256) {
    float v = __uint_as_float(((unsigned)xr[i]) << 16);
    v = fabsf(v);
    if (!(v < 1e30f)) v = 1e30f;  // NaN/inf -> huge
    mx = fmaxf(mx, v);
  }
  red[threadIdx.x] = mx;
  __syncthreads();
  for (int s = 128; s > 0; s >>= 1) {
    if (threadIdx.x < s) red[threadIdx.x] = fmaxf(red[threadIdx.x], red[threadIdx.x + s]);
    __syncthreads();
  }
  int isf = red[0] > 1e3f ? 1 : 0;
  if (blockIdx.x == 0 && threadIdx.x == 0) ((int*)(ws + O_FLAG))[0] = isf;

  int idx = blockIdx.x * 256 + threadIdx.x;
  if (idx < (int)N_XF) { ws[O_XF + idx] = load_in(x, idx, isf); return; }
  idx -= (int)N_XF;
  if (idx < 96) {  // W0: O=32,C=3
    int o = idx / 3, c = idx - o * 3;
    float a = load_in(W0, o * 6 + c, isf);
    float bb = load_in(W0, o * 6 + 3 + c, isf);
    ws[O_WP0 + c * 64 + o] = a;
    ws[O_WP0 + c * 64 + 32 + o] = bb - a;
    return;
  }
  idx -= 96;
  if (idx < 2048) {  // W1: O=64,C=32
    int o = idx >> 5, c = idx & 31;
    float a = load_in(W1, o * 64 + c, isf);
    float bb = load_in(W1, o * 64 + 32 + c, isf);
    ws[O_WP1 + c * 128 + o] = a;
    ws[O_WP1 + c * 128 + 64 + o] = bb - a;
    return;
  }
  idx -= 2048;
  if (idx < 8192) {  // W2: O=128,C=64
    int o = idx >> 6, c = idx & 63;
    float a = load_in(W2, o * 128 + c, isf);
    float bb = load_in(W2, o * 128 + 64 + c, isf);
    ws[O_WP2 + c * 256 + o] = a;
    ws[O_WP2 + c * 256 + 128 + o] = bb - a;
    return;
  }
  idx -= 8192;
  if (idx < 32768) {  // W3: O=256,C=128
    int o = idx >> 7, c = idx & 127;
    float a = load_in(W3, o * 256 + c, isf);
    float bb = load_in(W3, o * 256 + 128 + c, isf);
    ws[O_WP3 + c * 512 + o] = a;
    ws[O_WP3 + c * 512 + 256 + o] = bb - a;
    return;
  }
  idx -= 32768;
  if (idx < 61440) {  // Wh [128][480] -> [480][128]
    int o = idx / 480, c = idx - o * 480;
    ws[O_WHT + c * 128 + o] = load_in(Wh, idx, isf);
    return;
  }
  idx -= 61440;
  if (idx < 16384) { ws[O_F1W + idx] = load_in(fc1w, idx, isf); return; }
  idx -= 16384;
  if (idx < 128) { ws[O_F1B + idx] = load_in(fc1b, idx, isf); return; }
  idx -= 128;
  if (idx < 16384) { ws[O_F2W + idx] = load_in(fc2w, idx, isf); return; }
  idx -= 16384;
  if (idx < 128) { ws[O_F2B + idx] = load_in(fc2b, idx, isf); return; }
  idx -= 128;
  if (idx < (int)N_ZERO) ws[O_CS0 + idx] = 0.f;
}

// ---------------------------------------------------------------- dist (sq fused)
template <int C>
__global__ __launch_bounds__(256) void dist_kernel(const float* __restrict__ h, int hstride,
                                                   float* __restrict__ dist) {
  constexpr int CW = 16;
  __shared__ float Ast[CW][132];
  __shared__ float Bst[CW][132];
  __shared__ float sqn[128], sqm[128];
  int b = blockIdx.z;
  int n0 = blockIdx.y * 128, m0 = blockIdx.x * 128;
  int tid = threadIdx.x;
  int tx = tid & 15, ty = tid >> 4;
  int rr = tid & 127;
  float dot[8][8] = {};
  float sqacc = 0.f;
  for (int cc = 0; cc < C; cc += CW) {
    for (int i = tid; i < 128 * CW; i += 256) {
      int c = i & 15, r = i >> 4;
      int gc = cc + c;
      float av = 0.f, bv = 0.f;
      if (gc < C) {
        av = h[(size_t)(b * N + n0 + r) * hstride + gc];
        bv = h[(size_t)(b * N + m0 + r) * hstride + gc];
      }
      Ast[c][r] = av;
      Bst[c][r] = bv;
    }
    __syncthreads();
    if (tid < 128) {
#pragma unroll
      for (int c = 0; c < CW; ++c) { float v = Ast[c][rr]; sqacc += v * v; }
    } else {
#pragma unroll
      for (int c = 0; c < CW; ++c) { float v = Bst[c][rr]; sqacc += v * v; }
    }
#pragma unroll
    for (int c = 0; c < CW; ++c) {
      float4 a0 = *reinterpret_cast<const float4*>(&Ast[c][ty * 8]);
      float4 a1 = *reinterpret_cast<const float4*>(&Ast[c][ty * 8 + 4]);
      float4 b0 = *reinterpret_cast<const float4*>(&Bst[c][tx * 4]);
      float4 b1 = *reinterpret_cast<const float4*>(&Bst[c][64 + tx * 4]);
      float av[8] = {a0.x, a0.y, a0.z, a0.w, a1.x, a1.y, a1.z, a1.w};
      float bv[8] = {b0.x, b0.y, b0.z, b0.w, b1.x, b1.y, b1.z, b1.w};
#pragma unroll
      for (int i = 0; i < 8; ++i)
#pragma unroll
        for (int j = 0; j < 8; ++j) dot[i][j] += av[i] * bv[j];
    }
    __syncthreads();
  }
  if (tid < 128) sqn[rr] = sqacc; else sqm[rr] = sqacc;
  __syncthreads();
#pragma unroll
  for (int i = 0; i < 8; ++i) {
    int nn = n0 + ty * 8 + i;
    float sn = sqn[ty * 8 + i];
    float4 w;
    w.x = sn + sqm[tx * 4 + 0] - 2.f * dot[i][0];
    w.y = sn + sqm[tx * 4 + 1] - 2.f * dot[i][1];
    w.z = sn + sqm[tx * 4 + 2] - 2.f * dot[i][2];
    w.w = sn + sqm[tx * 4 + 3] - 2.f * dot[i][3];
    *reinterpret_cast<float4*>(&dist[(size_t)(b * N + nn) * N + m0 + tx * 4]) = w;
    float4 w2;
    w2.x = sn + sqm[64 + tx * 4 + 0] - 2.f * dot[i][4];
    w2.y = sn + sqm[64 + tx * 4 + 1] - 2.f * dot[i][5];
    w2.z = sn + sqm[64 + tx * 4 + 2] - 2.f * dot[i][6];
    w2.w = sn + sqm[64 + tx * 4 + 3] - 2.f * dot[i][7];
    *reinterpret_cast<float4*>(&dist[(size_t)(b * N + nn) * N + m0 + 64 + tx * 4]) = w2;
  }
}

__device__ __forceinline__ unsigned long long wave_min_u64(unsigned long long v) {
#pragma unroll
  for (int m = 1; m < 64; m <<= 1) {
    unsigned lo = (unsigned)v;
    unsigned hi = (unsigned)(v >> 32);
    unsigned olo = (unsigned)__shfl_xor((int)lo, m, 64);
    unsigned ohi = (unsigned)__shfl_xor((int)hi, m, 64);
    unsigned long long ov = ((unsigned long long)ohi << 32) | olo;
    if (ov < v) v = ov;
  }
  return v;
}

#define ARGMIN32(dk, ld, lj)                                        \
  {                                                                 \
    unsigned kv0 = dk[0], kv1 = dk[8], kv2 = dk[16], kv3 = dk[24];  \
    int j0 = 0, j1 = 8, j2 = 16, j3 = 24;                           \
    _Pragma("unroll")                                               \
    for (int t = 1; t < 8; ++t) {                                   \
      if (dk[t] < kv0) { kv0 = dk[t]; j0 = t; }                     \
      if (dk[8 + t] < kv1) { kv1 = dk[8 + t]; j1 = 8 + t; }         \
      if (dk[16 + t] < kv2) { kv2 = dk[16 + t]; j2 = 16 + t; }      \
      if (dk[24 + t] < kv3) { kv3 = dk[24 + t]; j3 = 24 + t; }      \
    }                                                               \
    if (kv1 < kv0) { kv0 = kv1; j0 = j1; }                          \
    if (kv3 < kv2) { kv2 = kv3; j2 = j3; }                          \
    if (kv2 < kv0) { kv0 = kv2; j0 = j2; }                          \
    ld = kv0; lj = j0;                                              \
  }

// ---------------------------------------------------------------- fused select || proj
// SLAB=true writes proj in slab-major layout [NO2/16][B*N][16] so the edge
// stage can stream contiguous 16-channel slabs into LDS.
template <int C, int NO2, bool SLAB>
__global__ __launch_bounds__(256) void selproj_kernel(const float* __restrict__ dist,
                                                      int* __restrict__ idxb,
                                                      const float* __restrict__ h,
                                                      int hstride,
                                                      const float* __restrict__ Wp,
                                                      float* __restrict__ projb) {
  constexpr int NSEL = B * N / 4;
  constexpr int MT = NO2 / 64;
  constexpr int CW = 16;
  __shared__ float As[64][17];
  __shared__ float Bs[64][17];
  if (blockIdx.x < NSEL) {
    int row = blockIdx.x * 4 + (threadIdx.x >> 6);  // b*N + n
    int lane = threadIdx.x & 63;
    const float* drow = dist + (size_t)row * N;
    unsigned dk[32];
#pragma unroll
    for (int j = 0; j < 32; ++j) {
      unsigned u = __float_as_uint(drow[j * 64 + lane]);
      dk[j] = (u & 0x80000000u) ? ~u : (u | 0x80000000u);
    }
    unsigned ld;
    int lj;
    ARGMIN32(dk, ld, lj);
    unsigned saved = 0;
    for (int it = 0; it <= KNN; ++it) {
      unsigned long long lkey =
          ((unsigned long long)ld << 32) | (unsigned)(lj * 64 + lane);
      unsigned long long g = wave_min_u64(lkey);
      if (it > 0 && lane == it - 1) saved = (unsigned)(g & 0xFFFFFFFFull);
      if (lkey == g) {  // unique m per lane -> exactly one winner
#pragma unroll
        for (int j = 0; j < 32; ++j)
          if (j == lj) dk[j] = 0xFFFFFFFFu;
        ARGMIN32(dk, ld, lj);
      }
    }
    if (lane < KNN) idxb[row * KNN + lane] = (int)saved;
  } else {
    int tile = blockIdx.x - NSEL;
    int m0 = (tile % MT) * 64;
    int n0 = (tile / MT) * 64;
    int tid = threadIdx.x;
    int tx = tid & 15, ty = tid >> 4;
    float dot[4][4] = {};
    for (int cc = 0; cc < C; cc += CW) {
      for (int i = tid; i < 64 * CW; i += 256) {
        int r = i >> 4, c = i & 15;
        int gc = cc + c;
        As[r][c] = (gc < C) ? h[(size_t)(n0 + r) * hstride + gc] : 0.f;
      }
      for (int i = tid; i < 64 * CW; i += 256) {
        int c = i >> 6, m = i & 63;
        int gc = cc + c;
        Bs[m][c] = (gc < C) ? Wp[(size_t)gc * NO2 + m0 + m] : 0.f;
      }
      __syncthreads();
#pragma unroll
      for (int c = 0; c < CW; ++c) {
        float av[4], bv[4];
#pragma unroll
        for (int i = 0; i < 4; ++i) av[i] = As[ty * 4 + i][c];
#pragma unroll
        for (int j = 0; j < 4; ++j) bv[j] = Bs[tx * 4 + j][c];
#pragma unroll
        for (int i = 0; i < 4; ++i)
#pragma unroll
          for (int j = 0; j < 4; ++j) dot[i][j] += av[i] * bv[j];
      }
      __syncthreads();
    }
#pragma unroll
    for (int i = 0; i < 4; ++i) {
      float4 wv;
      wv.x = dot[i][0];
      wv.y = dot[i][1];
      wv.z = dot[i][2];
      wv.w = dot[i][3];
      if constexpr (SLAB) {
        int m = m0 + tx * 4;  // m&15 in {0,4,8,12}: float4 stays within one slab
        size_t base = ((size_t)(m >> 4) * (B * N) + (size_t)(n0 + ty * 4 + i)) * 16 + (m & 15);
        *reinterpret_cast<float4*>(&projb[base]) = wv;
      } else {
        *reinterpret_cast<float4*>(&projb[(size_t)(n0 + ty * 4 + i) * NO2 + m0 + tx * 4]) = wv;
      }
    }
  }
}

// ---------------------------------------------------------------- edge reduce (small O)
// R16 path, kept for O=32/64 where gather volume is small.
template <int O>
__global__ __launch_bounds__(256) void edge_reduce_kernel(const float* __restrict__ proj,
                                                          const int* __restrict__ idxb,
                                                          float* __restrict__ cstats,
                                                          float* __restrict__ featdst) {
  constexpr int Q = O / 4;
  constexpr int TG = 256 / Q;
  constexpr int KS = KNN / TG;
  constexpr int G = 64 / Q;
  constexpr int NW = 4;
  constexpr int NO2 = 2 * O;
  __shared__ int knn[KNN];
  __shared__ float4 red[3][NW][Q];
  int bn = blockIdx.x;
  int b = bn >> 11;
  int tid = threadIdx.x;
  int w = tid >> 6;
  int lane = tid & 63;
  int g = lane / Q;
  int q = lane - g * Q;
  int kg = w * G + g;
  if (tid < KNN) knn[tid] = idxb[bn * KNN + tid];
  __syncthreads();
  int jbase = b << 11;
  const float4 h0 = *reinterpret_cast<const float4*>(&proj[(size_t)bn * NO2 + O + q * 4]);
  float4 mx = {-3.4e38f, -3.4e38f, -3.4e38f, -3.4e38f};
  float4 s = {0.f, 0.f, 0.f, 0.f}, ss = {0.f, 0.f, 0.f, 0.f};

  float4 v[KS];
#pragma unroll
  for (int t = 0; t < KS; ++t) {
    int j = jbase + knn[kg * KS + t];
    v[t] = *reinterpret_cast<const float4*>(&proj[(size_t)j * NO2 + q * 4]);
  }
#pragma unroll
  for (int t = 0; t < KS; ++t) {
    float ex = v[t].x + h0.x, ey = v[t].y + h0.y, ez = v[t].z + h0.z, ew = v[t].w + h0.w;
    s.x += ex; ss.x += ex * ex; mx.x = fmaxf(mx.x, ex);
    s.y += ey; ss.y += ey * ey; mx.y = fmaxf(mx.y, ey);
    s.z += ez; ss.z += ez * ez; mx.z = fmaxf(mx.z, ez);
    s.w += ew; ss.w += ew * ew; mx.w = fmaxf(mx.w, ew);
  }

  if constexpr (G > 1) {
#pragma unroll
    for (int m = Q; m < 64; m <<= 1) {
      mx.x = fmaxf(mx.x, __shfl_xor(mx.x, m, 64));
      mx.y = fmaxf(mx.y, __shfl_xor(mx.y, m, 64));
      mx.z = fmaxf(mx.z, __shfl_xor(mx.z, m, 64));
      mx.w = fmaxf(mx.w, __shfl_xor(mx.w, m, 64));
      s.x += __shfl_xor(s.x, m, 64);
      s.y += __shfl_xor(s.y, m, 64);
      s.z += __shfl_xor(s.z, m, 64);
      s.w += __shfl_xor(s.w, m, 64);
      ss.x += __shfl_xor(ss.x, m, 64);
      ss.y += __shfl_xor(ss.y, m, 64);
      ss.z += __shfl_xor(ss.z, m, 64);
      ss.w += __shfl_xor(ss.w, m, 64);
    }
  }
  if (lane < Q) {
    red[0][w][q] = mx;
    red[1][w][q] = s;
    red[2][w][q] = ss;
  }
  __syncthreads();
  if (tid < Q) {
    float4 M = red[0][0][tid], S = red[1][0][tid], SS = red[2][0][tid];
#pragma unroll
    for (int r = 1; r < NW; ++r) {
      float4 a = red[0][r][tid], c0 = red[1][r][tid], c1 = red[2][r][tid];
      M.x = fmaxf(M.x, a.x); M.y = fmaxf(M.y, a.y);
      M.z = fmaxf(M.z, a.z); M.w = fmaxf(M.w, a.w);
      S.x += c0.x; S.y += c0.y; S.z += c0.z; S.w += c0.w;
      SS.x += c1.x; SS.y += c1.y; SS.z += c1.z; SS.w += c1.w;
    }
    *reinterpret_cast<float4*>(&featdst[(size_t)bn * FD + tid * 4]) = M;
    int rep = bn & (REP - 1);
    float* cs = cstats + (size_t)rep * (B * O * 2) + (size_t)(b * O + tid * 4) * 2;
    atomicAdd(&cs[0], S.x);
    atomicAdd(&cs[1], SS.x);
    atomicAdd(&cs[2], S.y);
    atomicAdd(&cs[3], SS.y);
    atomicAdd(&cs[4], S.z);
    atomicAdd(&cs[5], SS.z);
    atomicAdd(&cs[6], S.w);
    atomicAdd(&cs[7], SS.w);
  }
}

// ---------------------------------------------------------------- edge reduce (slab, big O)
// R17: the 134 MB global gather runs at a hard ~1 TB/s (invariant across R1-R3
// structures) -> move the gather to LDS. Block = (point-split, 16-ch slab, b):
// streams slab [2048 pts][16 ch] (128 KB, contiguous in slab-major proj) into
// LDS, then gathers neighbors from LDS. Lane=(kq=lane>>4, ch=lane&15): per
// point 8 ds_read_b32 (16 ch-lanes -> 16 consecutive banks, <=4-way alias);
// max-reduce = 2 shuffles; s/ss accumulate per-lane across all points, one
// butterfly + 32 atomics per block. knn/h0 1-deep prefetched (1 block/CU).
template <int O, int NP>
__global__ __launch_bounds__(256) void edge_slab_kernel(const float* __restrict__ projs,
                                                        const int* __restrict__ idxb,
                                                        float* __restrict__ cstats,
                                                        float* __restrict__ featdst) {
  __shared__ float slab[2048 * 16];  // 128 KB
  __shared__ float redsm[2][4][16];
  int split = blockIdx.x, s = blockIdx.y, b = blockIdx.z;
  int tid = threadIdx.x, w = tid >> 6, lane = tid & 63;
  int kq = lane >> 4, ch = lane & 15;
  {
    const float4* src =
        (const float4*)(projs + ((size_t)s * (B * N) + (size_t)b * N) * 16);
    float4* dst = (float4*)slab;
#pragma unroll
    for (int i = 0; i < 32; ++i) dst[tid + i * 256] = src[tid + i * 256];
  }
  __syncthreads();
  const float* h0s = projs + (size_t)(O / 16 + s) * (B * N) * 16;
  int bn0 = b * N + split * NP;
  constexpr int NPW = NP / 4;
  float sum = 0.f, ssum = 0.f;
  int bn = bn0 + w;
  int4 j0n = *(const int4*)(idxb + (size_t)bn * KNN + kq * 8);
  int4 j1n = *(const int4*)(idxb + (size_t)bn * KNN + kq * 8 + 4);
  float h0n = h0s[(size_t)bn * 16 + ch];
  for (int p = 0; p < NPW; ++p) {
    int4 j0 = j0n, j1 = j1n;
    float h0 = h0n;
    int bncur = bn;
    if (p + 1 < NPW) {
      bn = bn0 + (p + 1) * 4 + w;
      j0n = *(const int4*)(idxb + (size_t)bn * KNN + kq * 8);
      j1n = *(const int4*)(idxb + (size_t)bn * KNN + kq * 8 + 4);
      h0n = h0s[(size_t)bn * 16 + ch];
    }
    float a0 = slab[j0.x * 16 + ch];
    float a1 = slab[j0.y * 16 + ch];
    float a2 = slab[j0.z * 16 + ch];
    float a3 = slab[j0.w * 16 + ch];
    float a4 = slab[j1.x * 16 + ch];
    float a5 = slab[j1.y * 16 + ch];
    float a6 = slab[j1.z * 16 + ch];
    float a7 = slab[j1.w * 16 + ch];
    float e0 = a0 + h0, e1 = a1 + h0, e2 = a2 + h0, e3 = a3 + h0;
    float e4 = a4 + h0, e5 = a5 + h0, e6 = a6 + h0, e7 = a7 + h0;
    sum += e0 + e1 + e2 + e3 + e4 + e5 + e6 + e7;
    ssum += e0 * e0 + e1 * e1 + e2 * e2 + e3 * e3 + e4 * e4 + e5 * e5 + e6 * e6 + e7 * e7;
    float mx = fmaxf(fmaxf(fmaxf(e0, e1), fmaxf(e2, e3)), fmaxf(fmaxf(e4, e5), fmaxf(e6, e7)));
    mx = fmaxf(mx, __shfl_xor(mx, 16, 64));
    mx = fmaxf(mx, __shfl_xor(mx, 32, 64));
    if (kq == 0) featdst[(size_t)bncur * FD + s * 16 + ch] = mx;
  }
  sum += __shfl_xor(sum, 16, 64);
  sum += __shfl_xor(sum, 32, 64);
  ssum += __shfl_xor(ssum, 16, 64);
  ssum += __shfl_xor(ssum, 32, 64);
  if (kq == 0) {
    redsm[0][w][ch] = sum;
    redsm[1][w][ch] = ssum;
  }
  __syncthreads();
  if (tid < 16) {
    float S = 0.f, SS = 0.f;
#pragma unroll
    for (int r = 0; r < 4; ++r) {
      S += redsm[0][r][tid];
      SS += redsm[1][r][tid];
    }
    int rep = split & (REP - 1);
    float* cs = cstats + ((size_t)rep * B + b) * O * 2 + (size_t)(s * 16 + tid) * 2;
    atomicAdd(&cs[0], S);
    atomicAdd(&cs[1], SS);
  }
}

// in-place: featdst = lrelu((featdst - mean) * rsqrt(var + eps)); folds REP replicas
__global__ void finalize_kernel(const float* __restrict__ cstats,
                                float* __restrict__ featdst, int O) {
  int i = blockIdx.x * 256 + threadIdx.x;
  int o = i % O;
  int bn = i / O;
  int b = bn >> 11;
  float s = 0.f, ss = 0.f;
#pragma unroll
  for (int r = 0; r < REP; ++r) {
    s += cstats[(size_t)r * (B * O * 2) + (size_t)(b * O + o) * 2 + 0];
    ss += cstats[(size_t)r * (B * O * 2) + (size_t)(b * O + o) * 2 + 1];
  }
  constexpr float inv = 1.f / ((float)N * KNN);
  float m = s * inv;
  float v = fmaxf(ss * inv - m * m, 0.f);
  float* p = &featdst[(size_t)bn * FD + o];
  float e = (*p - m) * rsqrtf(v + EPS);
  *p = lrelu(e);
}

// ---------------------------------------------------------------- 480 -> 128 stage
__global__ __launch_bounds__(256) void fstage_kernel(const float* __restrict__ feats,
                                                     const float* __restrict__ Wht,
                                                     float* __restrict__ fsum,
                                                     float* __restrict__ fss,
                                                     unsigned* __restrict__ fmaxu) {
  int blk = blockIdx.x;
  int b = blk >> 7;
  int n0 = (blk & 127) * 16;
  int tid = threadIdx.x;
  __shared__ float rows[16][FD];
  __shared__ float red[3][2][128];
  for (int i = tid; i < 16 * FD; i += 256) {
    int r = i / FD, c = i - r * FD;
    rows[r][c] = feats[(size_t)(b * N + n0 + r) * FD + c];
  }
  __syncthreads();
  int o = tid & 127, g = tid >> 7;
  float acc[8] = {};
  for (int c = 0; c < FD; c += 4) {
    float w0 = Wht[(c + 0) * 128 + o];
    float w1 = Wht[(c + 1) * 128 + o];
    float w2 = Wht[(c + 2) * 128 + o];
    float w3 = Wht[(c + 3) * 128 + o];
#pragma unroll
    for (int j = 0; j < 8; ++j) {
      float4 r4 = *reinterpret_cast<const float4*>(&rows[g * 8 + j][c]);
      acc[j] += w0 * r4.x + w1 * r4.y + w2 * r4.z + w3 * r4.w;
    }
  }
  float s = 0.f, ss = 0.f, mx = -3.4e38f;
#pragma unroll
  for (int j = 0; j < 8; ++j) {
    float f = acc[j];
    s += f;
    ss += f * f;
    mx = fmaxf(mx, f);
  }
  red[0][g][o] = s;
  red[1][g][o] = ss;
  red[2][g][o] = mx;
  __syncthreads();
  if (g == 0) {
    s += red[0][1][o];
    ss += red[1][1][o];
    mx = fmaxf(mx, red[2][1][o]);
    atomicAdd(&fsum[b * 128 + o], s);
    atomicAdd(&fss[b * 128 + o], ss);
    unsigned u = __float_as_uint(mx);
    u = (u & 0x80000000u) ? ~u : (u | 0x80000000u);
    atomicMax(&fmaxu[b * 128 + o], u);
  }
}

// ---------------------------------------------------------------- head
__global__ __launch_bounds__(128) void head_kernel(const float* __restrict__ fsum,
                                                   const float* __restrict__ fss,
                                                   const unsigned* __restrict__ fmaxu,
                                                   const float* __restrict__ fc1w,
                                                   const float* __restrict__ fc1b,
                                                   const float* __restrict__ fc2w,
                                                   const float* __restrict__ fc2b,
                                                   void* __restrict__ out,
                                                   const int* __restrict__ flag) {
  int b = blockIdx.x, o = threadIdx.x;
  __shared__ float gs[128], t1[128], ys[128];
  constexpr float invN = 1.f / N;
  float m = fsum[b * 128 + o] * invN;
  float v = fmaxf(fss[b * 128 + o] * invN - m * m, 0.f);
  unsigned u = fmaxu[b * 128 + o];
  unsigned bits = (u & 0x80000000u) ? (u ^ 0x80000000u) : ~u;
  float fx = __uint_as_float(bits);
  gs[o] = lrelu((fx - m) * rsqrtf(v + EPS));
  __syncthreads();
  float a = fc1b[o];
  for (int c = 0; c < 128; ++c) a += fc1w[o * 128 + c] * gs[c];
  t1[o] = a;
  __syncthreads();
  float mm = 0.f;
  for (int c = 0; c < 128; ++c) mm += t1[c];
  mm *= (1.f / 128);
  float vv = 0.f;
  for (int c = 0; c < 128; ++c) {
    float d = t1[c] - mm;
    vv += d * d;
  }
  vv *= (1.f / 128);
  ys[o] = lrelu((a - mm) * rsqrtf(vv + EPS));
  __syncthreads();
  float r = fc2b[o];
  for (int c = 0; c < 128; ++c) r += fc2w[o * 128 + c] * ys[c];
  if (flag[0])
    ((float*)out)[b * 128 + o] = r;
  else
    ((bf16*)out)[b * 128 + o] = __float2bfloat16(r);
}

// ---------------------------------------------------------------- driver
template <int C, int O, bool SLAB>
static void run_layer(const float* h, int hstride, float* featdst, const float* Wp,
                      float* cstats, float* dist, float* projb, int* idxb,
                      hipStream_t stream) {
  constexpr int NSEL = B * N / 4;
  constexpr int NPROJ = (2 * O / 64) * (B * N / 64);
  dist_kernel<C><<<dim3(N / 128, N / 128, B), 256, 0, stream>>>(h, hstride, dist);
  selproj_kernel<C, 2 * O, SLAB><<<NSEL + NPROJ, 256, 0, stream>>>(dist, idxb, h, hstride,
                                                                   Wp, projb);
  if constexpr (SLAB) {
    constexpr int NP = (O >= 256) ? 256 : 128;
    edge_slab_kernel<O, NP><<<dim3(N / NP, O / 16, B), 256, 0, stream>>>(projb, idxb,
                                                                         cstats, featdst);
  } else {
    edge_reduce_kernel<O><<<B * N, 256, 0, stream>>>(projb, idxb, cstats, featdst);
  }
  finalize_kernel<<<B * N * O / 256, 256, 0, stream>>>(cstats, featdst, O);
}

extern "C" void kernel_launch(void* const* d_in, const int* in_sizes, int n_in,
                              void* d_out, int out_size, void* d_ws, size_t ws_size,
                              hipStream_t stream) {
  float* ws = (float*)d_ws;
  float* xf = ws + O_XF;
  float* feats = ws + O_FEATS;
  float* dist = ws + O_DIST;
  float* projb = ws + O_PROJ;
  int* idxb = (int*)(ws + O_IDX);
  int* flag = (int*)(ws + O_FLAG);

  prep_kernel<<<(PREP_TOTAL + 255) / 256, 256, 0, stream>>>(
      d_in[0], d_in[2], d_in[3], d_in[4], d_in[5], d_in[6], d_in[7], d_in[8], d_in[9],
      d_in[10], ws);

  run_layer<3, 32, false>(xf, 3, feats + 0, ws + O_WP0, ws + O_CS0, dist, projb, idxb,
                          stream);
  run_layer<32, 64, false>(feats + 0, FD, feats + 32, ws + O_WP1, ws + O_CS1, dist, projb,
                           idxb, stream);
  run_layer<64, 128, true>(feats + 32, FD, feats + 96, ws + O_WP2, ws + O_CS2, dist, projb,
                           idxb, stream);
  run_layer<128, 256, true>(feats + 96, FD, feats + 224, ws + O_WP3, ws + O_CS3, dist,
                            projb, idxb, stream);

  fstage_kernel<<<B * 128, 256, 0, stream>>>(feats, ws + O_WHT, ws + O_FSUM, ws + O_FSS,
                                             (unsigned*)(ws + O_FMAX));
  head_kernel<<<B, 128, 0, stream>>>(ws + O_FSUM, ws + O_FSS, (unsigned*)(ws + O_FMAX),
                                     ws + O_F1W, ws + O_F1B, ws + O_F2W, ws + O_F2B, d_out,
                                     flag);
}

// Round 5
// 535.272 us; speedup vs baseline: 1.8454x; 1.2959x over previous
//
#include <hip/hip_runtime.h>
#include <hip/hip_bf16.h>
#include <cstdint>

using bf16 = __hip_bfloat16;

static constexpr int B = 2;
static constexpr int N = 2048;
static constexpr int KNN = 32;
static constexpr int FD = 480;
static constexpr float EPS = 1e-5f;
static constexpr float SLOPE = 0.2f;
static constexpr int REP = 8;  // cstats atomic replicas (contention spreading)

// ---------------- workspace layout (floats), all compile-time ----------------
static constexpr size_t N_XF = (size_t)B * N * 3;
static constexpr size_t N_FEATS = (size_t)B * N * FD;
static constexpr size_t N_DIST = (size_t)B * N * N;
static constexpr size_t N_IDX = (size_t)B * N * KNN;
static constexpr size_t N_PROJ = (size_t)B * N * 512;  // proj slab-major [2O/16][BN][16]
static constexpr size_t O_XF = 0;
static constexpr size_t O_FEATS = O_XF + N_XF;
static constexpr size_t O_DIST = O_FEATS + N_FEATS;
static constexpr size_t O_IDX = O_DIST + N_DIST;
static constexpr size_t O_PROJ = O_IDX + N_IDX;
static constexpr size_t O_WP0 = O_PROJ + N_PROJ;      // [3][64]
static constexpr size_t O_WP1 = O_WP0 + 192;          // [32][128]
static constexpr size_t O_WP2 = O_WP1 + 4096;         // [64][256]
static constexpr size_t O_WP3 = O_WP2 + 16384;        // [128][512]
static constexpr size_t O_WHT = O_WP3 + 65536;
static constexpr size_t O_F1W = O_WHT + 61440;
static constexpr size_t O_F1B = O_F1W + 16384;
static constexpr size_t O_F2W = O_F1B + 128;
static constexpr size_t O_F2B = O_F2W + 16384;
static constexpr size_t O_FLAG = O_F2B + 128;
static constexpr size_t O_CS0 = O_FLAG + 16;   // zero region starts here
// cstats per layer: REP * B * O * 2 floats
static constexpr size_t O_CS1 = O_CS0 + (size_t)REP * B * 32 * 2;    // +1024
static constexpr size_t O_CS2 = O_CS1 + (size_t)REP * B * 64 * 2;    // +2048
static constexpr size_t O_CS3 = O_CS2 + (size_t)REP * B * 128 * 2;   // +4096
static constexpr size_t O_FSUM = O_CS3 + (size_t)REP * B * 256 * 2;  // +8192
static constexpr size_t O_FSS = O_FSUM + 256;
static constexpr size_t O_FMAX = O_FSS + 256;
static constexpr size_t O_END = O_FMAX + 256;
static constexpr size_t N_ZERO = O_END - O_CS0;

__device__ __forceinline__ float lrelu(float x) { return x >= 0.f ? x : SLOPE * x; }

__device__ __forceinline__ float load_in(const void* p, int i, int isf32) {
  return isf32 ? ((const float*)p)[i] : __bfloat162float(((const bf16*)p)[i]);
}

// ---------------------------------------------------------------- prep (fused)
static constexpr int PREP_TOTAL =
    (int)(N_XF + 96 + 2048 + 8192 + 32768 + 61440 + 16384 + 128 + 16384 + 128 + N_ZERO);

__global__ __launch_bounds__(256) void prep_kernel(
    const void* __restrict__ x, const void* __restrict__ W0, const void* __restrict__ W1,
    const void* __restrict__ W2, const void* __restrict__ W3, const void* __restrict__ Wh,
    const void* __restrict__ fc1w, const void* __restrict__ fc1b,
    const void* __restrict__ fc2w, const void* __restrict__ fc2b, float* __restrict__ ws) {
  __shared__ float red[256];
  const unsigned short* xr = (const unsigned short*)x;
  float mx = 0.f;
  for (int i = threadIdx.x; i < B * N * 3; i += 256) {
    float v = __uint_as_float(((unsigned)xr[i]) << 16);
    v = fabsf(v);
    if (!(v < 1e30f)) v = 1e30f;  // NaN/inf -> huge
    mx = fmaxf(mx, v);
  }
  red[threadIdx.x] = mx;
  __syncthreads();
  for (int s = 128; s > 0; s >>= 1) {
    if (threadIdx.x < s) red[threadIdx.x] = fmaxf(red[threadIdx.x], red[threadIdx.x + s]);
    __syncthreads();
  }
  int isf = red[0] > 1e3f ? 1 : 0;
  if (blockIdx.x == 0 && threadIdx.x == 0) ((int*)(ws + O_FLAG))[0] = isf;

  int idx = blockIdx.x * 256 + threadIdx.x;
  if (idx < (int)N_XF) { ws[O_XF + idx] = load_in(x, idx, isf); return; }
  idx -= (int)N_XF;
  if (idx < 96) {  // W0: O=32,C=3
    int o = idx / 3, c = idx - o * 3;
    float a = load_in(W0, o * 6 + c, isf);
    float bb = load_in(W0, o * 6 + 3 + c, isf);
    ws[O_WP0 + c * 64 + o] = a;
    ws[O_WP0 + c * 64 + 32 + o] = bb - a;
    return;
  }
  idx -= 96;
  if (idx < 2048) {  // W1: O=64,C=32
    int o = idx >> 5, c = idx & 31;
    float a = load_in(W1, o * 64 + c, isf);
    float bb = load_in(W1, o * 64 + 32 + c, isf);
    ws[O_WP1 + c * 128 + o] = a;
    ws[O_WP1 + c * 128 + 64 + o] = bb - a;
    return;
  }
  idx -= 2048;
  if (idx < 8192) {  // W2: O=128,C=64
    int o = idx >> 6, c = idx & 63;
    float a = load_in(W2, o * 128 + c, isf);
    float bb = load_in(W2, o * 128 + 64 + c, isf);
    ws[O_WP2 + c * 256 + o] = a;
    ws[O_WP2 + c * 256 + 128 + o] = bb - a;
    return;
  }
  idx -= 8192;
  if (idx < 32768) {  // W3: O=256,C=128
    int o = idx >> 7, c = idx & 127;
    float a = load_in(W3, o * 256 + c, isf);
    float bb = load_in(W3, o * 256 + 128 + c, isf);
    ws[O_WP3 + c * 512 + o] = a;
    ws[O_WP3 + c * 512 + 256 + o] = bb - a;
    return;
  }
  idx -= 32768;
  if (idx < 61440) {  // Wh [128][480] -> [480][128]
    int o = idx / 480, c = idx - o * 480;
    ws[O_WHT + c * 128 + o] = load_in(Wh, idx, isf);
    return;
  }
  idx -= 61440;
  if (idx < 16384) { ws[O_F1W + idx] = load_in(fc1w, idx, isf); return; }
  idx -= 16384;
  if (idx < 128) { ws[O_F1B + idx] = load_in(fc1b, idx, isf); return; }
  idx -= 128;
  if (idx < 16384) { ws[O_F2W + idx] = load_in(fc2w, idx, isf); return; }
  idx -= 16384;
  if (idx < 128) { ws[O_F2B + idx] = load_in(fc2b, idx, isf); return; }
  idx -= 128;
  if (idx < (int)N_ZERO) ws[O_CS0 + idx] = 0.f;
}

// ---------------------------------------------------------------- dist (sq fused)
template <int C>
__global__ __launch_bounds__(256) void dist_kernel(const float* __restrict__ h, int hstride,
                                                   float* __restrict__ dist) {
  constexpr int CW = 16;
  __shared__ float Ast[CW][132];
  __shared__ float Bst[CW][132];
  __shared__ float sqn[128], sqm[128];
  int b = blockIdx.z;
  int n0 = blockIdx.y * 128, m0 = blockIdx.x * 128;
  int tid = threadIdx.x;
  int tx = tid & 15, ty = tid >> 4;
  int rr = tid & 127;
  float dot[8][8] = {};
  float sqacc = 0.f;
  for (int cc = 0; cc < C; cc += CW) {
    for (int i = tid; i < 128 * CW; i += 256) {
      int c = i & 15, r = i >> 4;
      int gc = cc + c;
      float av = 0.f, bv = 0.f;
      if (gc < C) {
        av = h[(size_t)(b * N + n0 + r) * hstride + gc];
        bv = h[(size_t)(b * N + m0 + r) * hstride + gc];
      }
      Ast[c][r] = av;
      Bst[c][r] = bv;
    }
    __syncthreads();
    if (tid < 128) {
#pragma unroll
      for (int c = 0; c < CW; ++c) { float v = Ast[c][rr]; sqacc += v * v; }
    } else {
#pragma unroll
      for (int c = 0; c < CW; ++c) { float v = Bst[c][rr]; sqacc += v * v; }
    }
#pragma unroll
    for (int c = 0; c < CW; ++c) {
      float4 a0 = *reinterpret_cast<const float4*>(&Ast[c][ty * 8]);
      float4 a1 = *reinterpret_cast<const float4*>(&Ast[c][ty * 8 + 4]);
      float4 b0 = *reinterpret_cast<const float4*>(&Bst[c][tx * 4]);
      float4 b1 = *reinterpret_cast<const float4*>(&Bst[c][64 + tx * 4]);
      float av[8] = {a0.x, a0.y, a0.z, a0.w, a1.x, a1.y, a1.z, a1.w};
      float bv[8] = {b0.x, b0.y, b0.z, b0.w, b1.x, b1.y, b1.z, b1.w};
#pragma unroll
      for (int i = 0; i < 8; ++i)
#pragma unroll
        for (int j = 0; j < 8; ++j) dot[i][j] += av[i] * bv[j];
    }
    __syncthreads();
  }
  if (tid < 128) sqn[rr] = sqacc; else sqm[rr] = sqacc;
  __syncthreads();
#pragma unroll
  for (int i = 0; i < 8; ++i) {
    int nn = n0 + ty * 8 + i;
    float sn = sqn[ty * 8 + i];
    float4 w;
    w.x = sn + sqm[tx * 4 + 0] - 2.f * dot[i][0];
    w.y = sn + sqm[tx * 4 + 1] - 2.f * dot[i][1];
    w.z = sn + sqm[tx * 4 + 2] - 2.f * dot[i][2];
    w.w = sn + sqm[tx * 4 + 3] - 2.f * dot[i][3];
    *reinterpret_cast<float4*>(&dist[(size_t)(b * N + nn) * N + m0 + tx * 4]) = w;
    float4 w2;
    w2.x = sn + sqm[64 + tx * 4 + 0] - 2.f * dot[i][4];
    w2.y = sn + sqm[64 + tx * 4 + 1] - 2.f * dot[i][5];
    w2.z = sn + sqm[64 + tx * 4 + 2] - 2.f * dot[i][6];
    w2.w = sn + sqm[64 + tx * 4 + 3] - 2.f * dot[i][7];
    *reinterpret_cast<float4*>(&dist[(size_t)(b * N + nn) * N + m0 + 64 + tx * 4]) = w2;
  }
}

__device__ __forceinline__ unsigned long long wave_min_u64(unsigned long long v) {
#pragma unroll
  for (int m = 1; m < 64; m <<= 1) {
    unsigned lo = (unsigned)v;
    unsigned hi = (unsigned)(v >> 32);
    unsigned olo = (unsigned)__shfl_xor((int)lo, m, 64);
    unsigned ohi = (unsigned)__shfl_xor((int)hi, m, 64);
    unsigned long long ov = ((unsigned long long)ohi << 32) | olo;
    if (ov < v) v = ov;
  }
  return v;
}

#define ARGMIN32(dk, ld, lj)                                        \
  {                                                                 \
    unsigned kv0 = dk[0], kv1 = dk[8], kv2 = dk[16], kv3 = dk[24];  \
    int j0 = 0, j1 = 8, j2 = 16, j3 = 24;                           \
    _Pragma("unroll")                                               \
    for (int t = 1; t < 8; ++t) {                                   \
      if (dk[t] < kv0) { kv0 = dk[t]; j0 = t; }                     \
      if (dk[8 + t] < kv1) { kv1 = dk[8 + t]; j1 = 8 + t; }         \
      if (dk[16 + t] < kv2) { kv2 = dk[16 + t]; j2 = 16 + t; }      \
      if (dk[24 + t] < kv3) { kv3 = dk[24 + t]; j3 = 24 + t; }      \
    }                                                               \
    if (kv1 < kv0) { kv0 = kv1; j0 = j1; }                          \
    if (kv3 < kv2) { kv2 = kv3; j2 = j3; }                          \
    if (kv2 < kv0) { kv0 = kv2; j0 = j2; }                          \
    ld = kv0; lj = j0;                                              \
  }

// ---------------------------------------------------------------- fused select || proj
// Writes proj in slab-major layout [2O/16][B*N][16] so the edge stage can
// stream contiguous 16-channel slabs into LDS.
template <int C, int NO2>
__global__ __launch_bounds__(256) void selproj_kernel(const float* __restrict__ dist,
                                                      int* __restrict__ idxb,
                                                      const float* __restrict__ h,
                                                      int hstride,
                                                      const float* __restrict__ Wp,
                                                      float* __restrict__ projb) {
  constexpr int NSEL = B * N / 4;
  constexpr int MT = NO2 / 64;
  constexpr int CW = 16;
  __shared__ float As[64][17];
  __shared__ float Bs[64][17];
  if (blockIdx.x < NSEL) {
    int row = blockIdx.x * 4 + (threadIdx.x >> 6);  // b*N + n
    int lane = threadIdx.x & 63;
    const float* drow = dist + (size_t)row * N;
    unsigned dk[32];
#pragma unroll
    for (int j = 0; j < 32; ++j) {
      unsigned u = __float_as_uint(drow[j * 64 + lane]);
      dk[j] = (u & 0x80000000u) ? ~u : (u | 0x80000000u);
    }
    unsigned ld;
    int lj;
    ARGMIN32(dk, ld, lj);
    unsigned saved = 0;
    for (int it = 0; it <= KNN; ++it) {
      unsigned long long lkey =
          ((unsigned long long)ld << 32) | (unsigned)(lj * 64 + lane);
      unsigned long long g = wave_min_u64(lkey);
      if (it > 0 && lane == it - 1) saved = (unsigned)(g & 0xFFFFFFFFull);
      if (lkey == g) {  // unique m per lane -> exactly one winner
#pragma unroll
        for (int j = 0; j < 32; ++j)
          if (j == lj) dk[j] = 0xFFFFFFFFu;
        ARGMIN32(dk, ld, lj);
      }
    }
    if (lane < KNN) idxb[row * KNN + lane] = (int)saved;
  } else {
    int tile = blockIdx.x - NSEL;
    int m0 = (tile % MT) * 64;
    int n0 = (tile / MT) * 64;
    int tid = threadIdx.x;
    int tx = tid & 15, ty = tid >> 4;
    float dot[4][4] = {};
    for (int cc = 0; cc < C; cc += CW) {
      for (int i = tid; i < 64 * CW; i += 256) {
        int r = i >> 4, c = i & 15;
        int gc = cc + c;
        As[r][c] = (gc < C) ? h[(size_t)(n0 + r) * hstride + gc] : 0.f;
      }
      for (int i = tid; i < 64 * CW; i += 256) {
        int c = i >> 6, m = i & 63;
        int gc = cc + c;
        Bs[m][c] = (gc < C) ? Wp[(size_t)gc * NO2 + m0 + m] : 0.f;
      }
      __syncthreads();
#pragma unroll
      for (int c = 0; c < CW; ++c) {
        float av[4], bv[4];
#pragma unroll
        for (int i = 0; i < 4; ++i) av[i] = As[ty * 4 + i][c];
#pragma unroll
        for (int j = 0; j < 4; ++j) bv[j] = Bs[tx * 4 + j][c];
#pragma unroll
        for (int i = 0; i < 4; ++i)
#pragma unroll
          for (int j = 0; j < 4; ++j) dot[i][j] += av[i] * bv[j];
      }
      __syncthreads();
    }
#pragma unroll
    for (int i = 0; i < 4; ++i) {
      float4 wv;
      wv.x = dot[i][0];
      wv.y = dot[i][1];
      wv.z = dot[i][2];
      wv.w = dot[i][3];
      int m = m0 + tx * 4;  // m&15 in {0,4,8,12}: float4 stays within one slab
      size_t base = ((size_t)(m >> 4) * (B * N) + (size_t)(n0 + ty * 4 + i)) * 16 + (m & 15);
      *reinterpret_cast<float4*>(&projb[base]) = wv;
    }
  }
}

// ---------------------------------------------------------------- edge reduce (slab)
// R17/R18: the scattered per-point row gather through L2 has a ~100us floor
// regardless of volume (R3/R4 evidence) -> gather from LDS instead, for ALL
// layers. Block = (point-split, 16-ch slab, b): streams slab [2048 pts][16 ch]
// (128 KB contiguous in slab-major proj) into LDS, then gathers neighbors from
// LDS. Lane=(kq=lane>>4, ch=lane&15): per point 8 ds_read_b32 (16 ch-lanes ->
// 16 consecutive banks, ~2-way alias = free); max-reduce = 2 shuffles; s/ss
// accumulate per-lane across points; one butterfly + 16 atomics per block.
template <int O, int NP>
__global__ __launch_bounds__(256) void edge_slab_kernel(const float* __restrict__ projs,
                                                        const int* __restrict__ idxb,
                                                        float* __restrict__ cstats,
                                                        float* __restrict__ featdst) {
  __shared__ float slab[2048 * 16];  // 128 KB
  __shared__ float redsm[2][4][16];
  int split = blockIdx.x, s = blockIdx.y, b = blockIdx.z;
  int tid = threadIdx.x, w = tid >> 6, lane = tid & 63;
  int kq = lane >> 4, ch = lane & 15;
  {
    const float4* src =
        (const float4*)(projs + ((size_t)s * (B * N) + (size_t)b * N) * 16);
    float4* dst = (float4*)slab;
#pragma unroll
    for (int i = 0; i < 32; ++i) dst[tid + i * 256] = src[tid + i * 256];
  }
  __syncthreads();
  const float* h0s = projs + (size_t)(O / 16 + s) * (B * N) * 16;
  int bn0 = b * N + split * NP;
  constexpr int NPW = NP / 4;
  float sum = 0.f, ssum = 0.f;
  int bn = bn0 + w;
  int4 j0n = *(const int4*)(idxb + (size_t)bn * KNN + kq * 8);
  int4 j1n = *(const int4*)(idxb + (size_t)bn * KNN + kq * 8 + 4);
  float h0n = h0s[(size_t)bn * 16 + ch];
  for (int p = 0; p < NPW; ++p) {
    int4 j0 = j0n, j1 = j1n;
    float h0 = h0n;
    int bncur = bn;
    if (p + 1 < NPW) {
      bn = bn0 + (p + 1) * 4 + w;
      j0n = *(const int4*)(idxb + (size_t)bn * KNN + kq * 8);
      j1n = *(const int4*)(idxb + (size_t)bn * KNN + kq * 8 + 4);
      h0n = h0s[(size_t)bn * 16 + ch];
    }
    float a0 = slab[j0.x * 16 + ch];
    float a1 = slab[j0.y * 16 + ch];
    float a2 = slab[j0.z * 16 + ch];
    float a3 = slab[j0.w * 16 + ch];
    float a4 = slab[j1.x * 16 + ch];
    float a5 = slab[j1.y * 16 + ch];
    float a6 = slab[j1.z * 16 + ch];
    float a7 = slab[j1.w * 16 + ch];
    float e0 = a0 + h0, e1 = a1 + h0, e2 = a2 + h0, e3 = a3 + h0;
    float e4 = a4 + h0, e5 = a5 + h0, e6 = a6 + h0, e7 = a7 + h0;
    sum += e0 + e1 + e2 + e3 + e4 + e5 + e6 + e7;
    ssum += e0 * e0 + e1 * e1 + e2 * e2 + e3 * e3 + e4 * e4 + e5 * e5 + e6 * e6 + e7 * e7;
    float mx = fmaxf(fmaxf(fmaxf(e0, e1), fmaxf(e2, e3)), fmaxf(fmaxf(e4, e5), fmaxf(e6, e7)));
    mx = fmaxf(mx, __shfl_xor(mx, 16, 64));
    mx = fmaxf(mx, __shfl_xor(mx, 32, 64));
    if (kq == 0) featdst[(size_t)bncur * FD + s * 16 + ch] = mx;
  }
  sum += __shfl_xor(sum, 16, 64);
  sum += __shfl_xor(sum, 32, 64);
  ssum += __shfl_xor(ssum, 16, 64);
  ssum += __shfl_xor(ssum, 32, 64);
  if (kq == 0) {
    redsm[0][w][ch] = sum;
    redsm[1][w][ch] = ssum;
  }
  __syncthreads();
  if (tid < 16) {
    float S = 0.f, SS = 0.f;
#pragma unroll
    for (int r = 0; r < 4; ++r) {
      S += redsm[0][r][tid];
      SS += redsm[1][r][tid];
    }
    int rep = split & (REP - 1);
    float* cs = cstats + ((size_t)rep * B + b) * O * 2 + (size_t)(s * 16 + tid) * 2;
    atomicAdd(&cs[0], S);
    atomicAdd(&cs[1], SS);
  }
}

// in-place: featdst = lrelu((featdst - mean) * rsqrt(var + eps)); folds REP replicas
__global__ void finalize_kernel(const float* __restrict__ cstats,
                                float* __restrict__ featdst, int O) {
  int i = blockIdx.x * 256 + threadIdx.x;
  int o = i % O;
  int bn = i / O;
  int b = bn >> 11;
  float s = 0.f, ss = 0.f;
#pragma unroll
  for (int r = 0; r < REP; ++r) {
    s += cstats[(size_t)r * (B * O * 2) + (size_t)(b * O + o) * 2 + 0];
    ss += cstats[(size_t)r * (B * O * 2) + (size_t)(b * O + o) * 2 + 1];
  }
  constexpr float inv = 1.f / ((float)N * KNN);
  float m = s * inv;
  float v = fmaxf(ss * inv - m * m, 0.f);
  float* p = &featdst[(size_t)bn * FD + o];
  float e = (*p - m) * rsqrtf(v + EPS);
  *p = lrelu(e);
}

// ---------------------------------------------------------------- 480 -> 128 stage
__global__ __launch_bounds__(256) void fstage_kernel(const float* __restrict__ feats,
                                                     const float* __restrict__ Wht,
                                                     float* __restrict__ fsum,
                                                     float* __restrict__ fss,
                                                     unsigned* __restrict__ fmaxu) {
  int blk = blockIdx.x;
  int b = blk >> 7;
  int n0 = (blk & 127) * 16;
  int tid = threadIdx.x;
  __shared__ float rows[16][FD];
  __shared__ float red[3][2][128];
  for (int i = tid; i < 16 * FD; i += 256) {
    int r = i / FD, c = i - r * FD;
    rows[r][c] = feats[(size_t)(b * N + n0 + r) * FD + c];
  }
  __syncthreads();
  int o = tid & 127, g = tid >> 7;
  float acc[8] = {};
  for (int c = 0; c < FD; c += 4) {
    float w0 = Wht[(c + 0) * 128 + o];
    float w1 = Wht[(c + 1) * 128 + o];
    float w2 = Wht[(c + 2) * 128 + o];
    float w3 = Wht[(c + 3) * 128 + o];
#pragma unroll
    for (int j = 0; j < 8; ++j) {
      float4 r4 = *reinterpret_cast<const float4*>(&rows[g * 8 + j][c]);
      acc[j] += w0 * r4.x + w1 * r4.y + w2 * r4.z + w3 * r4.w;
    }
  }
  float s = 0.f, ss = 0.f, mx = -3.4e38f;
#pragma unroll
  for (int j = 0; j < 8; ++j) {
    float f = acc[j];
    s += f;
    ss += f * f;
    mx = fmaxf(mx, f);
  }
  red[0][g][o] = s;
  red[1][g][o] = ss;
  red[2][g][o] = mx;
  __syncthreads();
  if (g == 0) {
    s += red[0][1][o];
    ss += red[1][1][o];
    mx = fmaxf(mx, red[2][1][o]);
    atomicAdd(&fsum[b * 128 + o], s);
    atomicAdd(&fss[b * 128 + o], ss);
    unsigned u = __float_as_uint(mx);
    u = (u & 0x80000000u) ? ~u : (u | 0x80000000u);
    atomicMax(&fmaxu[b * 128 + o], u);
  }
}

// ---------------------------------------------------------------- head
__global__ __launch_bounds__(128) void head_kernel(const float* __restrict__ fsum,
                                                   const float* __restrict__ fss,
                                                   const unsigned* __restrict__ fmaxu,
                                                   const float* __restrict__ fc1w,
                                                   const float* __restrict__ fc1b,
                                                   const float* __restrict__ fc2w,
                                                   const float* __restrict__ fc2b,
                                                   void* __restrict__ out,
                                                   const int* __restrict__ flag) {
  int b = blockIdx.x, o = threadIdx.x;
  __shared__ float gs[128], t1[128], ys[128];
  constexpr float invN = 1.f / N;
  float m = fsum[b * 128 + o] * invN;
  float v = fmaxf(fss[b * 128 + o] * invN - m * m, 0.f);
  unsigned u = fmaxu[b * 128 + o];
  unsigned bits = (u & 0x80000000u) ? (u ^ 0x80000000u) : ~u;
  float fx = __uint_as_float(bits);
  gs[o] = lrelu((fx - m) * rsqrtf(v + EPS));
  __syncthreads();
  float a = fc1b[o];
  for (int c = 0; c < 128; ++c) a += fc1w[o * 128 + c] * gs[c];
  t1[o] = a;
  __syncthreads();
  float mm = 0.f;
  for (int c = 0; c < 128; ++c) mm += t1[c];
  mm *= (1.f / 128);
  float vv = 0.f;
  for (int c = 0; c < 128; ++c) {
    float d = t1[c] - mm;
    vv += d * d;
  }
  vv *= (1.f / 128);
  ys[o] = lrelu((a - mm) * rsqrtf(vv + EPS));
  __syncthreads();
  float r = fc2b[o];
  for (int c = 0; c < 128; ++c) r += fc2w[o * 128 + c] * ys[c];
  if (flag[0])
    ((float*)out)[b * 128 + o] = r;
  else
    ((bf16*)out)[b * 128 + o] = __float2bfloat16(r);
}

// ---------------------------------------------------------------- driver
template <int C, int O>
static void run_layer(const float* h, int hstride, float* featdst, const float* Wp,
                      float* cstats, float* dist, float* projb, int* idxb,
                      hipStream_t stream) {
  constexpr int NSEL = B * N / 4;
  constexpr int NPROJ = (2 * O / 64) * (B * N / 64);
  dist_kernel<C><<<dim3(N / 128, N / 128, B), 256, 0, stream>>>(h, hstride, dist);
  selproj_kernel<C, 2 * O><<<NSEL + NPROJ, 256, 0, stream>>>(dist, idxb, h, hstride, Wp,
                                                             projb);
  constexpr int NP = (O >= 256) ? 256 : (O == 128 ? 128 : 64);
  edge_slab_kernel<O, NP><<<dim3(N / NP, O / 16, B), 256, 0, stream>>>(projb, idxb, cstats,
                                                                       featdst);
  finalize_kernel<<<B * N * O / 256, 256, 0, stream>>>(cstats, featdst, O);
}

extern "C" void kernel_launch(void* const* d_in, const int* in_sizes, int n_in,
                              void* d_out, int out_size, void* d_ws, size_t ws_size,
                              hipStream_t stream) {
  float* ws = (float*)d_ws;
  float* xf = ws + O_XF;
  float* feats = ws + O_FEATS;
  float* dist = ws + O_DIST;
  float* projb = ws + O_PROJ;
  int* idxb = (int*)(ws + O_IDX);
  int* flag = (int*)(ws + O_FLAG);

  prep_kernel<<<(PREP_TOTAL + 255) / 256, 256, 0, stream>>>(
      d_in[0], d_in[2], d_in[3], d_in[4], d_in[5], d_in[6], d_in[7], d_in[8], d_in[9],
      d_in[10], ws);

  run_layer<3, 32>(xf, 3, feats + 0, ws + O_WP0, ws + O_CS0, dist, projb, idxb, stream);
  run_layer<32, 64>(feats + 0, FD, feats + 32, ws + O_WP1, ws + O_CS1, dist, projb, idxb,
                    stream);
  run_layer<64, 128>(feats + 32, FD, feats + 96, ws + O_WP2, ws + O_CS2, dist, projb, idxb,
                     stream);
  run_layer<128, 256>(feats + 96, FD, feats + 224, ws + O_WP3, ws + O_CS3, dist, projb,
                      idxb, stream);

  fstage_kernel<<<B * 128, 256, 0, stream>>>(feats, ws + O_WHT, ws + O_FSUM, ws + O_FSS,
                                             (unsigned*)(ws + O_FMAX));
  head_kernel<<<B, 128, 0, stream>>>(ws + O_FSUM, ws + O_FSS, (unsigned*)(ws + O_FMAX),
                                     ws + O_F1W, ws + O_F1B, ws + O_F2W, ws + O_F2B, d_out,
                                     flag);
}

// Round 6
// 452.904 us; speedup vs baseline: 2.1810x; 1.1819x over previous
//
#include <hip/hip_runtime.h>
#include <hip/hip_bf16.h>
#include <cstdint>

using bf16 = __hip_bfloat16;

static constexpr int B = 2;
static constexpr int N = 2048;
static constexpr int KNN = 32;
static constexpr int FD = 480;
static constexpr float EPS = 1e-5f;
static constexpr float SLOPE = 0.2f;
static constexpr int REP = 8;  // cstats atomic replicas (contention spreading)

// ---------------- workspace layout (floats), all compile-time ----------------
static constexpr size_t N_XF = (size_t)B * N * 3;
static constexpr size_t N_FEATS = (size_t)B * N * FD;
static constexpr size_t N_DIST = (size_t)B * N * N;
static constexpr size_t N_IDX = (size_t)B * N * KNN;
static constexpr size_t N_PROJ = (size_t)B * N * 512;  // proj slab-major [2O/16][BN][16]
static constexpr size_t O_XF = 0;
static constexpr size_t O_FEATS = O_XF + N_XF;
static constexpr size_t O_DIST = O_FEATS + N_FEATS;
static constexpr size_t O_IDX = O_DIST + N_DIST;
static constexpr size_t O_PROJ = O_IDX + N_IDX;
static constexpr size_t O_WP0 = O_PROJ + N_PROJ;      // [3][64]
static constexpr size_t O_WP1 = O_WP0 + 192;          // [32][128]
static constexpr size_t O_WP2 = O_WP1 + 4096;         // [64][256]
static constexpr size_t O_WP3 = O_WP2 + 16384;        // [128][512]
static constexpr size_t O_WHT = O_WP3 + 65536;
static constexpr size_t O_F1W = O_WHT + 61440;
static constexpr size_t O_F1B = O_F1W + 16384;
static constexpr size_t O_F2W = O_F1B + 128;
static constexpr size_t O_F2B = O_F2W + 16384;
static constexpr size_t O_FLAG = O_F2B + 128;
static constexpr size_t O_CS0 = O_FLAG + 16;   // zero region starts here
// cstats per layer: REP * B * O * 2 floats
static constexpr size_t O_CS1 = O_CS0 + (size_t)REP * B * 32 * 2;    // +1024
static constexpr size_t O_CS2 = O_CS1 + (size_t)REP * B * 64 * 2;    // +2048
static constexpr size_t O_CS3 = O_CS2 + (size_t)REP * B * 128 * 2;   // +4096
static constexpr size_t O_FSUM = O_CS3 + (size_t)REP * B * 256 * 2;  // +8192
static constexpr size_t O_FSS = O_FSUM + 256;
static constexpr size_t O_FMAX = O_FSS + 256;
static constexpr size_t O_END = O_FMAX + 256;
static constexpr size_t N_ZERO = O_END - O_CS0;

__device__ __forceinline__ float lrelu(float x) { return x >= 0.f ? x : SLOPE * x; }

__device__ __forceinline__ float load_in(const void* p, int i, int isf32) {
  return isf32 ? ((const float*)p)[i] : __bfloat162float(((const bf16*)p)[i]);
}

// ---------------------------------------------------------------- prep (fused)
static constexpr int PREP_TOTAL =
    (int)(N_XF + 96 + 2048 + 8192 + 32768 + 61440 + 16384 + 128 + 16384 + 128 + N_ZERO);

__global__ __launch_bounds__(256) void prep_kernel(
    const void* __restrict__ x, const void* __restrict__ W0, const void* __restrict__ W1,
    const void* __restrict__ W2, const void* __restrict__ W3, const void* __restrict__ Wh,
    const void* __restrict__ fc1w, const void* __restrict__ fc1b,
    const void* __restrict__ fc2w, const void* __restrict__ fc2b, float* __restrict__ ws) {
  __shared__ float red[256];
  const unsigned short* xr = (const unsigned short*)x;
  float mx = 0.f;
  for (int i = threadIdx.x; i < B * N * 3; i += 256) {
    float v = __uint_as_float(((unsigned)xr[i]) << 16);
    v = fabsf(v);
    if (!(v < 1e30f)) v = 1e30f;  // NaN/inf -> huge
    mx = fmaxf(mx, v);
  }
  red[threadIdx.x] = mx;
  __syncthreads();
  for (int s = 128; s > 0; s >>= 1) {
    if (threadIdx.x < s) red[threadIdx.x] = fmaxf(red[threadIdx.x], red[threadIdx.x + s]);
    __syncthreads();
  }
  int isf = red[0] > 1e3f ? 1 : 0;
  if (blockIdx.x == 0 && threadIdx.x == 0) ((int*)(ws + O_FLAG))[0] = isf;

  int idx = blockIdx.x * 256 + threadIdx.x;
  if (idx < (int)N_XF) { ws[O_XF + idx] = load_in(x, idx, isf); return; }
  idx -= (int)N_XF;
  if (idx < 96) {  // W0: O=32,C=3
    int o = idx / 3, c = idx - o * 3;
    float a = load_in(W0, o * 6 + c, isf);
    float bb = load_in(W0, o * 6 + 3 + c, isf);
    ws[O_WP0 + c * 64 + o] = a;
    ws[O_WP0 + c * 64 + 32 + o] = bb - a;
    return;
  }
  idx -= 96;
  if (idx < 2048) {  // W1: O=64,C=32
    int o = idx >> 5, c = idx & 31;
    float a = load_in(W1, o * 64 + c, isf);
    float bb = load_in(W1, o * 64 + 32 + c, isf);
    ws[O_WP1 + c * 128 + o] = a;
    ws[O_WP1 + c * 128 + 64 + o] = bb - a;
    return;
  }
  idx -= 2048;
  if (idx < 8192) {  // W2: O=128,C=64
    int o = idx >> 6, c = idx & 63;
    float a = load_in(W2, o * 128 + c, isf);
    float bb = load_in(W2, o * 128 + 64 + c, isf);
    ws[O_WP2 + c * 256 + o] = a;
    ws[O_WP2 + c * 256 + 128 + o] = bb - a;
    return;
  }
  idx -= 8192;
  if (idx < 32768) {  // W3: O=256,C=128
    int o = idx >> 7, c = idx & 127;
    float a = load_in(W3, o * 256 + c, isf);
    float bb = load_in(W3, o * 256 + 128 + c, isf);
    ws[O_WP3 + c * 512 + o] = a;
    ws[O_WP3 + c * 512 + 256 + o] = bb - a;
    return;
  }
  idx -= 32768;
  if (idx < 61440) {  // Wh [128][480] -> [480][128]
    int o = idx / 480, c = idx - o * 480;
    ws[O_WHT + c * 128 + o] = load_in(Wh, idx, isf);
    return;
  }
  idx -= 61440;
  if (idx < 16384) { ws[O_F1W + idx] = load_in(fc1w, idx, isf); return; }
  idx -= 16384;
  if (idx < 128) { ws[O_F1B + idx] = load_in(fc1b, idx, isf); return; }
  idx -= 128;
  if (idx < 16384) { ws[O_F2W + idx] = load_in(fc2w, idx, isf); return; }
  idx -= 16384;
  if (idx < 128) { ws[O_F2B + idx] = load_in(fc2b, idx, isf); return; }
  idx -= 128;
  if (idx < (int)N_ZERO) ws[O_CS0 + idx] = 0.f;
}

// ---------------------------------------------------------------- dist (sq fused)
template <int C>
__global__ __launch_bounds__(256) void dist_kernel(const float* __restrict__ h, int hstride,
                                                   float* __restrict__ dist) {
  constexpr int CW = 16;
  __shared__ float Ast[CW][132];
  __shared__ float Bst[CW][132];
  __shared__ float sqn[128], sqm[128];
  int b = blockIdx.z;
  int n0 = blockIdx.y * 128, m0 = blockIdx.x * 128;
  int tid = threadIdx.x;
  int tx = tid & 15, ty = tid >> 4;
  int rr = tid & 127;
  float dot[8][8] = {};
  float sqacc = 0.f;
  for (int cc = 0; cc < C; cc += CW) {
    for (int i = tid; i < 128 * CW; i += 256) {
      int c = i & 15, r = i >> 4;
      int gc = cc + c;
      float av = 0.f, bv = 0.f;
      if (gc < C) {
        av = h[(size_t)(b * N + n0 + r) * hstride + gc];
        bv = h[(size_t)(b * N + m0 + r) * hstride + gc];
      }
      Ast[c][r] = av;
      Bst[c][r] = bv;
    }
    __syncthreads();
    if (tid < 128) {
#pragma unroll
      for (int c = 0; c < CW; ++c) { float v = Ast[c][rr]; sqacc += v * v; }
    } else {
#pragma unroll
      for (int c = 0; c < CW; ++c) { float v = Bst[c][rr]; sqacc += v * v; }
    }
#pragma unroll
    for (int c = 0; c < CW; ++c) {
      float4 a0 = *reinterpret_cast<const float4*>(&Ast[c][ty * 8]);
      float4 a1 = *reinterpret_cast<const float4*>(&Ast[c][ty * 8 + 4]);
      float4 b0 = *reinterpret_cast<const float4*>(&Bst[c][tx * 4]);
      float4 b1 = *reinterpret_cast<const float4*>(&Bst[c][64 + tx * 4]);
      float av[8] = {a0.x, a0.y, a0.z, a0.w, a1.x, a1.y, a1.z, a1.w};
      float bv[8] = {b0.x, b0.y, b0.z, b0.w, b1.x, b1.y, b1.z, b1.w};
#pragma unroll
      for (int i = 0; i < 8; ++i)
#pragma unroll
        for (int j = 0; j < 8; ++j) dot[i][j] += av[i] * bv[j];
    }
    __syncthreads();
  }
  if (tid < 128) sqn[rr] = sqacc; else sqm[rr] = sqacc;
  __syncthreads();
#pragma unroll
  for (int i = 0; i < 8; ++i) {
    int nn = n0 + ty * 8 + i;
    float sn = sqn[ty * 8 + i];
    float4 w;
    w.x = sn + sqm[tx * 4 + 0] - 2.f * dot[i][0];
    w.y = sn + sqm[tx * 4 + 1] - 2.f * dot[i][1];
    w.z = sn + sqm[tx * 4 + 2] - 2.f * dot[i][2];
    w.w = sn + sqm[tx * 4 + 3] - 2.f * dot[i][3];
    *reinterpret_cast<float4*>(&dist[(size_t)(b * N + nn) * N + m0 + tx * 4]) = w;
    float4 w2;
    w2.x = sn + sqm[64 + tx * 4 + 0] - 2.f * dot[i][4];
    w2.y = sn + sqm[64 + tx * 4 + 1] - 2.f * dot[i][5];
    w2.z = sn + sqm[64 + tx * 4 + 2] - 2.f * dot[i][6];
    w2.w = sn + sqm[64 + tx * 4 + 3] - 2.f * dot[i][7];
    *reinterpret_cast<float4*>(&dist[(size_t)(b * N + nn) * N + m0 + 64 + tx * 4]) = w2;
  }
}

__device__ __forceinline__ unsigned long long wave_min_u64(unsigned long long v) {
#pragma unroll
  for (int m = 1; m < 64; m <<= 1) {
    unsigned lo = (unsigned)v;
    unsigned hi = (unsigned)(v >> 32);
    unsigned olo = (unsigned)__shfl_xor((int)lo, m, 64);
    unsigned ohi = (unsigned)__shfl_xor((int)hi, m, 64);
    unsigned long long ov = ((unsigned long long)ohi << 32) | olo;
    if (ov < v) v = ov;
  }
  return v;
}

#define ARGMIN32(dk, ld, lj)                                        \
  {                                                                 \
    unsigned kv0 = dk[0], kv1 = dk[8], kv2 = dk[16], kv3 = dk[24];  \
    int j0 = 0, j1 = 8, j2 = 16, j3 = 24;                           \
    _Pragma("unroll")                                               \
    for (int t = 1; t < 8; ++t) {                                   \
      if (dk[t] < kv0) { kv0 = dk[t]; j0 = t; }                     \
      if (dk[8 + t] < kv1) { kv1 = dk[8 + t]; j1 = 8 + t; }         \
      if (dk[16 + t] < kv2) { kv2 = dk[16 + t]; j2 = 16 + t; }      \
      if (dk[24 + t] < kv3) { kv3 = dk[24 + t]; j3 = 24 + t; }      \
    }                                                               \
    if (kv1 < kv0) { kv0 = kv1; j0 = j1; }                          \
    if (kv3 < kv2) { kv2 = kv3; j2 = j3; }                          \
    if (kv2 < kv0) { kv0 = kv2; j0 = j2; }                          \
    ld = kv0; lj = j0;                                              \
  }

// 64-lane bitonic sort, ascending toward lane 0 (u32 keys).
__device__ __forceinline__ unsigned bitonic64_u32(unsigned v, int lane) {
#pragma unroll
  for (int k = 2; k <= 64; k <<= 1) {
#pragma unroll
    for (int j = k >> 1; j > 0; j >>= 1) {
      unsigned o = (unsigned)__shfl_xor((int)v, j, 64);
      bool up = (lane & k) == 0;
      bool lower = (lane & j) == 0;
      bool keepmin = (up == lower);
      unsigned mn = v < o ? v : o;
      unsigned mx = v < o ? o : v;
      v = keepmin ? mn : mx;
    }
  }
  return v;
}

// 64-lane bitonic sort of (hi,lo) u64 keys, ascending lexicographic toward lane 0.
__device__ __forceinline__ void bitonic64_u64(unsigned& hi, unsigned& lo, int lane) {
#pragma unroll
  for (int k = 2; k <= 64; k <<= 1) {
#pragma unroll
    for (int j = k >> 1; j > 0; j >>= 1) {
      unsigned ohi = (unsigned)__shfl_xor((int)hi, j, 64);
      unsigned olo = (unsigned)__shfl_xor((int)lo, j, 64);
      bool up = (lane & k) == 0;
      bool lower = (lane & j) == 0;
      bool keepmin = (up == lower);
      bool lt = (hi < ohi) || (hi == ohi && lo < olo);  // self < other
      bool take_other = keepmin ? !lt : lt;
      if (take_other) { hi = ohi; lo = olo; }
    }
  }
}

// ---------------------------------------------------------------- fused select || proj
// R19 select: filter+sort replaces 33 serial wave-min extractions (67us, VALU/
// latency-bound, ~3300 wave-ops + 6000cy shfl chain per row). T = rank-32 of
// the 64 sorted lane-mins is a provable upper bound on the true 33rd-smallest
// (33 lanes at sorted ranks 0..32 contribute >=1 value <= T each). Compact
// survivors (~46 expected) into a 64-slot LDS arena, one u64 bitonic sort of
// (key,idx) -> lanes 1..32 emit neighbors. Exact: same (key,index) lex order
// as the iterative path (bitwise-identical output). Survivors>64 -> old exact
// iterative fallback (block-uniform barriers keep fast/slow waves deadlock-free).
template <int C, int NO2>
__global__ __launch_bounds__(256) void selproj_kernel(const float* __restrict__ dist,
                                                      int* __restrict__ idxb,
                                                      const float* __restrict__ h,
                                                      int hstride,
                                                      const float* __restrict__ Wp,
                                                      float* __restrict__ projb) {
  constexpr int NSEL = B * N / 4;
  constexpr int MT = NO2 / 64;
  constexpr int CW = 16;
  __shared__ float As[64][17];
  __shared__ float Bs[64][17];
  if (blockIdx.x < NSEL) {
    int row = blockIdx.x * 4 + (threadIdx.x >> 6);  // b*N + n
    int lane = threadIdx.x & 63;
    const float* drow = dist + (size_t)row * N;
    unsigned dk[32];
#pragma unroll
    for (int j = 0; j < 32; ++j) {
      unsigned u = __float_as_uint(drow[j * 64 + lane]);
      dk[j] = (u & 0x80000000u) ? ~u : (u | 0x80000000u);
    }
    // ---- threshold T = rank-32 of the 64 lane-mins ----
    unsigned lmin0 = dk[0], lmin1 = dk[1];
#pragma unroll
    for (int j = 2; j < 32; j += 2) {
      lmin0 = lmin0 < dk[j] ? lmin0 : dk[j];
      lmin1 = lmin1 < dk[j + 1] ? lmin1 : dk[j + 1];
    }
    unsigned lmin = lmin0 < lmin1 ? lmin0 : lmin1;
    unsigned srt = bitonic64_u32(lmin, lane);
    unsigned T = (unsigned)__shfl((int)srt, 32, 64);
    // ---- count survivors + prefix offsets ----
    unsigned cnt = 0;
#pragma unroll
    for (int j = 0; j < 32; ++j) cnt += (dk[j] <= T) ? 1u : 0u;
    unsigned inc = cnt;
#pragma unroll
    for (int d = 1; d < 64; d <<= 1) {
      unsigned t = (unsigned)__shfl_up((int)inc, d, 64);
      if (lane >= d) inc += t;
    }
    unsigned tot = (unsigned)__shfl((int)inc, 63, 64);
    unsigned off = inc - cnt;
    bool fast = tot <= 64u;  // wave-uniform
    // arena (reuses As/Bs: 256 u32 slots each, block has 4 waves x 64 slots)
    unsigned* aHi = reinterpret_cast<unsigned*>(&As[0][0]);
    unsigned* aLo = reinterpret_cast<unsigned*>(&Bs[0][0]);
    int wbase = (threadIdx.x >> 6) * 64;
    aHi[wbase + lane] = 0xFFFFFFFFu;
    aLo[wbase + lane] = 0xFFFFFFFFu;
    __syncthreads();
    if (fast) {
      unsigned o = off;
#pragma unroll
      for (int j = 0; j < 32; ++j) {
        if (dk[j] <= T) {
          aHi[wbase + o] = dk[j];
          aLo[wbase + o] = (unsigned)(j * 64 + lane);
          ++o;
        }
      }
    }
    __syncthreads();
    if (fast) {
      unsigned hi = aHi[wbase + lane];
      unsigned lo = aLo[wbase + lane];
      bitonic64_u64(hi, lo, lane);
      if (lane >= 1 && lane <= KNN) idxb[row * KNN + lane - 1] = (int)lo;
    } else {
      // exact iterative fallback (rare: >64 values tie below/at T)
      unsigned ld;
      int lj;
      ARGMIN32(dk, ld, lj);
      unsigned saved = 0;
      for (int it = 0; it <= KNN; ++it) {
        unsigned long long lkey =
            ((unsigned long long)ld << 32) | (unsigned)(lj * 64 + lane);
        unsigned long long g = wave_min_u64(lkey);
        if (it > 0 && lane == it - 1) saved = (unsigned)(g & 0xFFFFFFFFull);
        if (lkey == g) {
#pragma unroll
          for (int j = 0; j < 32; ++j)
            if (j == lj) dk[j] = 0xFFFFFFFFu;
          ARGMIN32(dk, ld, lj);
        }
      }
      if (lane < KNN) idxb[row * KNN + lane] = (int)saved;
    }
  } else {
    int tile = blockIdx.x - NSEL;
    int m0 = (tile % MT) * 64;
    int n0 = (tile / MT) * 64;
    int tid = threadIdx.x;
    int tx = tid & 15, ty = tid >> 4;
    float dot[4][4] = {};
    for (int cc = 0; cc < C; cc += CW) {
      for (int i = tid; i < 64 * CW; i += 256) {
        int r = i >> 4, c = i & 15;
        int gc = cc + c;
        As[r][c] = (gc < C) ? h[(size_t)(n0 + r) * hstride + gc] : 0.f;
      }
      for (int i = tid; i < 64 * CW; i += 256) {
        int c = i >> 6, m = i & 63;
        int gc = cc + c;
        Bs[m][c] = (gc < C) ? Wp[(size_t)gc * NO2 + m0 + m] : 0.f;
      }
      __syncthreads();
#pragma unroll
      for (int c = 0; c < CW; ++c) {
        float av[4], bv[4];
#pragma unroll
        for (int i = 0; i < 4; ++i) av[i] = As[ty * 4 + i][c];
#pragma unroll
        for (int j = 0; j < 4; ++j) bv[j] = Bs[tx * 4 + j][c];
#pragma unroll
        for (int i = 0; i < 4; ++i)
#pragma unroll
          for (int j = 0; j < 4; ++j) dot[i][j] += av[i] * bv[j];
      }
      __syncthreads();
    }
#pragma unroll
    for (int i = 0; i < 4; ++i) {
      float4 wv;
      wv.x = dot[i][0];
      wv.y = dot[i][1];
      wv.z = dot[i][2];
      wv.w = dot[i][3];
      int m = m0 + tx * 4;  // m&15 in {0,4,8,12}: float4 stays within one slab
      size_t base = ((size_t)(m >> 4) * (B * N) + (size_t)(n0 + ty * 4 + i)) * 16 + (m & 15);
      *reinterpret_cast<float4*>(&projb[base]) = wv;
    }
  }
}

// ---------------------------------------------------------------- edge reduce (slab)
template <int O, int NP>
__global__ __launch_bounds__(256) void edge_slab_kernel(const float* __restrict__ projs,
                                                        const int* __restrict__ idxb,
                                                        float* __restrict__ cstats,
                                                        float* __restrict__ featdst) {
  __shared__ float slab[2048 * 16];  // 128 KB
  __shared__ float redsm[2][4][16];
  int split = blockIdx.x, s = blockIdx.y, b = blockIdx.z;
  int tid = threadIdx.x, w = tid >> 6, lane = tid & 63;
  int kq = lane >> 4, ch = lane & 15;
  {
    const float4* src =
        (const float4*)(projs + ((size_t)s * (B * N) + (size_t)b * N) * 16);
    float4* dst = (float4*)slab;
#pragma unroll
    for (int i = 0; i < 32; ++i) dst[tid + i * 256] = src[tid + i * 256];
  }
  __syncthreads();
  const float* h0s = projs + (size_t)(O / 16 + s) * (B * N) * 16;
  int bn0 = b * N + split * NP;
  constexpr int NPW = NP / 4;
  float sum = 0.f, ssum = 0.f;
  int bn = bn0 + w;
  int4 j0n = *(const int4*)(idxb + (size_t)bn * KNN + kq * 8);
  int4 j1n = *(const int4*)(idxb + (size_t)bn * KNN + kq * 8 + 4);
  float h0n = h0s[(size_t)bn * 16 + ch];
  for (int p = 0; p < NPW; ++p) {
    int4 j0 = j0n, j1 = j1n;
    float h0 = h0n;
    int bncur = bn;
    if (p + 1 < NPW) {
      bn = bn0 + (p + 1) * 4 + w;
      j0n = *(const int4*)(idxb + (size_t)bn * KNN + kq * 8);
      j1n = *(const int4*)(idxb + (size_t)bn * KNN + kq * 8 + 4);
      h0n = h0s[(size_t)bn * 16 + ch];
    }
    float a0 = slab[j0.x * 16 + ch];
    float a1 = slab[j0.y * 16 + ch];
    float a2 = slab[j0.z * 16 + ch];
    float a3 = slab[j0.w * 16 + ch];
    float a4 = slab[j1.x * 16 + ch];
    float a5 = slab[j1.y * 16 + ch];
    float a6 = slab[j1.z * 16 + ch];
    float a7 = slab[j1.w * 16 + ch];
    float e0 = a0 + h0, e1 = a1 + h0, e2 = a2 + h0, e3 = a3 + h0;
    float e4 = a4 + h0, e5 = a5 + h0, e6 = a6 + h0, e7 = a7 + h0;
    sum += e0 + e1 + e2 + e3 + e4 + e5 + e6 + e7;
    ssum += e0 * e0 + e1 * e1 + e2 * e2 + e3 * e3 + e4 * e4 + e5 * e5 + e6 * e6 + e7 * e7;
    float mx = fmaxf(fmaxf(fmaxf(e0, e1), fmaxf(e2, e3)), fmaxf(fmaxf(e4, e5), fmaxf(e6, e7)));
    mx = fmaxf(mx, __shfl_xor(mx, 16, 64));
    mx = fmaxf(mx, __shfl_xor(mx, 32, 64));
    if (kq == 0) featdst[(size_t)bncur * FD + s * 16 + ch] = mx;
  }
  sum += __shfl_xor(sum, 16, 64);
  sum += __shfl_xor(sum, 32, 64);
  ssum += __shfl_xor(ssum, 16, 64);
  ssum += __shfl_xor(ssum, 32, 64);
  if (kq == 0) {
    redsm[0][w][ch] = sum;
    redsm[1][w][ch] = ssum;
  }
  __syncthreads();
  if (tid < 16) {
    float S = 0.f, SS = 0.f;
#pragma unroll
    for (int r = 0; r < 4; ++r) {
      S += redsm[0][r][tid];
      SS += redsm[1][r][tid];
    }
    int rep = split & (REP - 1);
    float* cs = cstats + ((size_t)rep * B + b) * O * 2 + (size_t)(s * 16 + tid) * 2;
    atomicAdd(&cs[0], S);
    atomicAdd(&cs[1], SS);
  }
}

// in-place: featdst = lrelu((featdst - mean) * rsqrt(var + eps)); folds REP replicas
__global__ void finalize_kernel(const float* __restrict__ cstats,
                                float* __restrict__ featdst, int O) {
  int i = blockIdx.x * 256 + threadIdx.x;
  int o = i % O;
  int bn = i / O;
  int b = bn >> 11;
  float s = 0.f, ss = 0.f;
#pragma unroll
  for (int r = 0; r < REP; ++r) {
    s += cstats[(size_t)r * (B * O * 2) + (size_t)(b * O + o) * 2 + 0];
    ss += cstats[(size_t)r * (B * O * 2) + (size_t)(b * O + o) * 2 + 1];
  }
  constexpr float inv = 1.f / ((float)N * KNN);
  float m = s * inv;
  float v = fmaxf(ss * inv - m * m, 0.f);
  float* p = &featdst[(size_t)bn * FD + o];
  float e = (*p - m) * rsqrtf(v + EPS);
  *p = lrelu(e);
}

// ---------------------------------------------------------------- 480 -> 128 stage
__global__ __launch_bounds__(256) void fstage_kernel(const float* __restrict__ feats,
                                                     const float* __restrict__ Wht,
                                                     float* __restrict__ fsum,
                                                     float* __restrict__ fss,
                                                     unsigned* __restrict__ fmaxu) {
  int blk = blockIdx.x;
  int b = blk >> 7;
  int n0 = (blk & 127) * 16;
  int tid = threadIdx.x;
  __shared__ float rows[16][FD];
  __shared__ float red[3][2][128];
  for (int i = tid; i < 16 * FD; i += 256) {
    int r = i / FD, c = i - r * FD;
    rows[r][c] = feats[(size_t)(b * N + n0 + r) * FD + c];
  }
  __syncthreads();
  int o = tid & 127, g = tid >> 7;
  float acc[8] = {};
  for (int c = 0; c < FD; c += 4) {
    float w0 = Wht[(c + 0) * 128 + o];
    float w1 = Wht[(c + 1) * 128 + o];
    float w2 = Wht[(c + 2) * 128 + o];
    float w3 = Wht[(c + 3) * 128 + o];
#pragma unroll
    for (int j = 0; j < 8; ++j) {
      float4 r4 = *reinterpret_cast<const float4*>(&rows[g * 8 + j][c]);
      acc[j] += w0 * r4.x + w1 * r4.y + w2 * r4.z + w3 * r4.w;
    }
  }
  float s = 0.f, ss = 0.f, mx = -3.4e38f;
#pragma unroll
  for (int j = 0; j < 8; ++j) {
    float f = acc[j];
    s += f;
    ss += f * f;
    mx = fmaxf(mx, f);
  }
  red[0][g][o] = s;
  red[1][g][o] = ss;
  red[2][g][o] = mx;
  __syncthreads();
  if (g == 0) {
    s += red[0][1][o];
    ss += red[1][1][o];
    mx = fmaxf(mx, red[2][1][o]);
    atomicAdd(&fsum[b * 128 + o], s);
    atomicAdd(&fss[b * 128 + o], ss);
    unsigned u = __float_as_uint(mx);
    u = (u & 0x80000000u) ? ~u : (u | 0x80000000u);
    atomicMax(&fmaxu[b * 128 + o], u);
  }
}

// ---------------------------------------------------------------- head
__global__ __launch_bounds__(128) void head_kernel(const float* __restrict__ fsum,
                                                   const float* __restrict__ fss,
                                                   const unsigned* __restrict__ fmaxu,
                                                   const float* __restrict__ fc1w,
                                                   const float* __restrict__ fc1b,
                                                   const float* __restrict__ fc2w,
                                                   const float* __restrict__ fc2b,
                                                   void* __restrict__ out,
                                                   const int* __restrict__ flag) {
  int b = blockIdx.x, o = threadIdx.x;
  __shared__ float gs[128], t1[128], ys[128];
  constexpr float invN = 1.f / N;
  float m = fsum[b * 128 + o] * invN;
  float v = fmaxf(fss[b * 128 + o] * invN - m * m, 0.f);
  unsigned u = fmaxu[b * 128 + o];
  unsigned bits = (u & 0x80000000u) ? (u ^ 0x80000000u) : ~u;
  float fx = __uint_as_float(bits);
  gs[o] = lrelu((fx - m) * rsqrtf(v + EPS));
  __syncthreads();
  float a = fc1b[o];
  for (int c = 0; c < 128; ++c) a += fc1w[o * 128 + c] * gs[c];
  t1[o] = a;
  __syncthreads();
  float mm = 0.f;
  for (int c = 0; c < 128; ++c) mm += t1[c];
  mm *= (1.f / 128);
  float vv = 0.f;
  for (int c = 0; c < 128; ++c) {
    float d = t1[c] - mm;
    vv += d * d;
  }
  vv *= (1.f / 128);
  ys[o] = lrelu((a - mm) * rsqrtf(vv + EPS));
  __syncthreads();
  float r = fc2b[o];
  for (int c = 0; c < 128; ++c) r += fc2w[o * 128 + c] * ys[c];
  if (flag[0])
    ((float*)out)[b * 128 + o] = r;
  else
    ((bf16*)out)[b * 128 + o] = __float2bfloat16(r);
}

// ---------------------------------------------------------------- driver
template <int C, int O>
static void run_layer(const float* h, int hstride, float* featdst, const float* Wp,
                      float* cstats, float* dist, float* projb, int* idxb,
                      hipStream_t stream) {
  constexpr int NSEL = B * N / 4;
  constexpr int NPROJ = (2 * O / 64) * (B * N / 64);
  dist_kernel<C><<<dim3(N / 128, N / 128, B), 256, 0, stream>>>(h, hstride, dist);
  selproj_kernel<C, 2 * O><<<NSEL + NPROJ, 256, 0, stream>>>(dist, idxb, h, hstride, Wp,
                                                             projb);
  constexpr int NP = (O >= 256) ? 256 : (O == 128 ? 128 : 64);
  edge_slab_kernel<O, NP><<<dim3(N / NP, O / 16, B), 256, 0, stream>>>(projb, idxb, cstats,
                                                                       featdst);
  finalize_kernel<<<B * N * O / 256, 256, 0, stream>>>(cstats, featdst, O);
}

extern "C" void kernel_launch(void* const* d_in, const int* in_sizes, int n_in,
                              void* d_out, int out_size, void* d_ws, size_t ws_size,
                              hipStream_t stream) {
  float* ws = (float*)d_ws;
  float* xf = ws + O_XF;
  float* feats = ws + O_FEATS;
  float* dist = ws + O_DIST;
  float* projb = ws + O_PROJ;
  int* idxb = (int*)(ws + O_IDX);
  int* flag = (int*)(ws + O_FLAG);

  prep_kernel<<<(PREP_TOTAL + 255) / 256, 256, 0, stream>>>(
      d_in[0], d_in[2], d_in[3], d_in[4], d_in[5], d_in[6], d_in[7], d_in[8], d_in[9],
      d_in[10], ws);

  run_layer<3, 32>(xf, 3, feats + 0, ws + O_WP0, ws + O_CS0, dist, projb, idxb, stream);
  run_layer<32, 64>(feats + 0, FD, feats + 32, ws + O_WP1, ws + O_CS1, dist, projb, idxb,
                    stream);
  run_layer<64, 128>(feats + 32, FD, feats + 96, ws + O_WP2, ws + O_CS2, dist, projb, idxb,
                     stream);
  run_layer<128, 256>(feats + 96, FD, feats + 224, ws + O_WP3, ws + O_CS3, dist, projb,
                      idxb, stream);

  fstage_kernel<<<B * 128, 256, 0, stream>>>(feats, ws + O_WHT, ws + O_FSUM, ws + O_FSS,
                                             (unsigned*)(ws + O_FMAX));
  head_kernel<<<B, 128, 0, stream>>>(ws + O_FSUM, ws + O_FSS, (unsigned*)(ws + O_FMAX),
                                     ws + O_F1W, ws + O_F1B, ws + O_F2W, ws + O_F2B, d_out,
                                     flag);
}

// Round 7
// 382.083 us; speedup vs baseline: 2.5852x; 1.1854x over previous
//
#include <hip/hip_runtime.h>
#include <hip/hip_bf16.h>
#include <cstdint>

using bf16 = __hip_bfloat16;

static constexpr int B = 2;
static constexpr int N = 2048;
static constexpr int KNN = 32;
static constexpr int FD = 480;
static constexpr float EPS = 1e-5f;
static constexpr float SLOPE = 0.2f;
static constexpr int REP = 8;  // cstats atomic replicas (contention spreading)

// ---------------- workspace layout (floats), all compile-time ----------------
static constexpr size_t N_XF = (size_t)B * N * 3;
static constexpr size_t N_FEATS = (size_t)B * N * FD;
static constexpr size_t N_DIST = (size_t)B * N * N;
static constexpr size_t N_IDX = (size_t)B * N * KNN;
static constexpr size_t N_PROJ = (size_t)B * N * 512;  // proj slab-major [2O/16][BN][16]
static constexpr size_t O_XF = 0;
static constexpr size_t O_FEATS = O_XF + N_XF;
static constexpr size_t O_DIST = O_FEATS + N_FEATS;
static constexpr size_t O_IDX = O_DIST + N_DIST;
static constexpr size_t O_PROJ = O_IDX + N_IDX;
static constexpr size_t O_WP0 = O_PROJ + N_PROJ;      // [3][64]
static constexpr size_t O_WP1 = O_WP0 + 192;          // [32][128]
static constexpr size_t O_WP2 = O_WP1 + 4096;         // [64][256]
static constexpr size_t O_WP3 = O_WP2 + 16384;        // [128][512]
static constexpr size_t O_WHT = O_WP3 + 65536;
static constexpr size_t O_F1W = O_WHT + 61440;
static constexpr size_t O_F1B = O_F1W + 16384;
static constexpr size_t O_F2W = O_F1B + 128;
static constexpr size_t O_F2B = O_F2W + 16384;
static constexpr size_t O_FLAG = O_F2B + 128;
static constexpr size_t O_CS0 = O_FLAG + 16;   // zero region starts here
// cstats per layer: REP * B * O * 2 floats
static constexpr size_t O_CS1 = O_CS0 + (size_t)REP * B * 32 * 2;    // +1024
static constexpr size_t O_CS2 = O_CS1 + (size_t)REP * B * 64 * 2;    // +2048
static constexpr size_t O_CS3 = O_CS2 + (size_t)REP * B * 128 * 2;   // +4096
static constexpr size_t O_FSUM = O_CS3 + (size_t)REP * B * 256 * 2;  // +8192
static constexpr size_t O_FSS = O_FSUM + 256;
static constexpr size_t O_FMAX = O_FSS + 256;
static constexpr size_t O_END = O_FMAX + 256;
static constexpr size_t N_ZERO = O_END - O_CS0;

__device__ __forceinline__ float lrelu(float x) { return x >= 0.f ? x : SLOPE * x; }

__device__ __forceinline__ float load_in(const void* p, int i, int isf32) {
  return isf32 ? ((const float*)p)[i] : __bfloat162float(((const bf16*)p)[i]);
}

// ---------------------------------------------------------------- prep (fused)
static constexpr int PREP_TOTAL =
    (int)(N_XF + 96 + 2048 + 8192 + 32768 + 61440 + 16384 + 128 + 16384 + 128 + N_ZERO);

__global__ __launch_bounds__(256) void prep_kernel(
    const void* __restrict__ x, const void* __restrict__ W0, const void* __restrict__ W1,
    const void* __restrict__ W2, const void* __restrict__ W3, const void* __restrict__ Wh,
    const void* __restrict__ fc1w, const void* __restrict__ fc1b,
    const void* __restrict__ fc2w, const void* __restrict__ fc2b, float* __restrict__ ws) {
  __shared__ float red[256];
  const unsigned short* xr = (const unsigned short*)x;
  float mx = 0.f;
  for (int i = threadIdx.x; i < B * N * 3; i += 256) {
    float v = __uint_as_float(((unsigned)xr[i]) << 16);
    v = fabsf(v);
    if (!(v < 1e30f)) v = 1e30f;  // NaN/inf -> huge
    mx = fmaxf(mx, v);
  }
  red[threadIdx.x] = mx;
  __syncthreads();
  for (int s = 128; s > 0; s >>= 1) {
    if (threadIdx.x < s) red[threadIdx.x] = fmaxf(red[threadIdx.x], red[threadIdx.x + s]);
    __syncthreads();
  }
  int isf = red[0] > 1e3f ? 1 : 0;
  if (blockIdx.x == 0 && threadIdx.x == 0) ((int*)(ws + O_FLAG))[0] = isf;

  int idx = blockIdx.x * 256 + threadIdx.x;
  if (idx < (int)N_XF) { ws[O_XF + idx] = load_in(x, idx, isf); return; }
  idx -= (int)N_XF;
  if (idx < 96) {  // W0: O=32,C=3
    int o = idx / 3, c = idx - o * 3;
    float a = load_in(W0, o * 6 + c, isf);
    float bb = load_in(W0, o * 6 + 3 + c, isf);
    ws[O_WP0 + c * 64 + o] = a;
    ws[O_WP0 + c * 64 + 32 + o] = bb - a;
    return;
  }
  idx -= 96;
  if (idx < 2048) {  // W1: O=64,C=32
    int o = idx >> 5, c = idx & 31;
    float a = load_in(W1, o * 64 + c, isf);
    float bb = load_in(W1, o * 64 + 32 + c, isf);
    ws[O_WP1 + c * 128 + o] = a;
    ws[O_WP1 + c * 128 + 64 + o] = bb - a;
    return;
  }
  idx -= 2048;
  if (idx < 8192) {  // W2: O=128,C=64
    int o = idx >> 6, c = idx & 63;
    float a = load_in(W2, o * 128 + c, isf);
    float bb = load_in(W2, o * 128 + 64 + c, isf);
    ws[O_WP2 + c * 256 + o] = a;
    ws[O_WP2 + c * 256 + 128 + o] = bb - a;
    return;
  }
  idx -= 8192;
  if (idx < 32768) {  // W3: O=256,C=128
    int o = idx >> 7, c = idx & 127;
    float a = load_in(W3, o * 256 + c, isf);
    float bb = load_in(W3, o * 256 + 128 + c, isf);
    ws[O_WP3 + c * 512 + o] = a;
    ws[O_WP3 + c * 512 + 256 + o] = bb - a;
    return;
  }
  idx -= 32768;
  if (idx < 61440) {  // Wh [128][480] -> [480][128]
    int o = idx / 480, c = idx - o * 480;
    ws[O_WHT + c * 128 + o] = load_in(Wh, idx, isf);
    return;
  }
  idx -= 61440;
  if (idx < 16384) { ws[O_F1W + idx] = load_in(fc1w, idx, isf); return; }
  idx -= 16384;
  if (idx < 128) { ws[O_F1B + idx] = load_in(fc1b, idx, isf); return; }
  idx -= 128;
  if (idx < 16384) { ws[O_F2W + idx] = load_in(fc2w, idx, isf); return; }
  idx -= 16384;
  if (idx < 128) { ws[O_F2B + idx] = load_in(fc2b, idx, isf); return; }
  idx -= 128;
  if (idx < (int)N_ZERO) ws[O_CS0 + idx] = 0.f;
}

// ---------------------------------------------------------------- dist (sq fused)
// R20: 64x128 tiles -> grid 1024 (4 blocks/CU, ~16 waves/CU) vs old 128x128
// grid 512 (2/CU, 18% occupancy, VALU 31% -- grid-limited latency exposure).
// Thread tile 4n x 8m; A-fragment read is wave-broadcast (conflict-free).
// Staging loads are aligned float4 when C%16==0 (hstride=480); C=3 keeps the
// scalar guarded path (12 B row stride cannot be vectorized).
template <int C>
__global__ __launch_bounds__(256) void dist_kernel(const float* __restrict__ h, int hstride,
                                                   float* __restrict__ dist) {
  constexpr int CW = 16;
  __shared__ float Ast[CW][68];    // 64 rows + 4 pad (16B-aligned row stride)
  __shared__ float Bst[CW][132];   // 128 rows + 4 pad
  __shared__ float sqn[64], sqm[128];
  int b = blockIdx.z;
  int n0 = blockIdx.y * 64, m0 = blockIdx.x * 128;
  int tid = threadIdx.x;
  int tx = tid & 15, ty = tid >> 4;  // tx: m-group (8 cols), ty: n-group (4 rows)
  float dot[4][8] = {};
  float sqa = 0.f;
  for (int cc = 0; cc < C; cc += CW) {
    if constexpr (C % CW == 0) {
      int r = tid >> 2, cq = (tid & 3) * 4;
      float4 va = *reinterpret_cast<const float4*>(
          &h[(size_t)(b * N + n0 + r) * hstride + cc + cq]);
      Ast[cq + 0][r] = va.x;
      Ast[cq + 1][r] = va.y;
      Ast[cq + 2][r] = va.z;
      Ast[cq + 3][r] = va.w;
#pragma unroll
      for (int k = 0; k < 2; ++k) {
        int i = tid + k * 256;
        int rB = i >> 2, cqB = (i & 3) * 4;
        float4 vb = *reinterpret_cast<const float4*>(
            &h[(size_t)(b * N + m0 + rB) * hstride + cc + cqB]);
        Bst[cqB + 0][rB] = vb.x;
        Bst[cqB + 1][rB] = vb.y;
        Bst[cqB + 2][rB] = vb.z;
        Bst[cqB + 3][rB] = vb.w;
      }
    } else {
      for (int i = tid; i < 64 * CW; i += 256) {
        int c = i & 15, r = i >> 4;
        int gc = cc + c;
        Ast[c][r] = (gc < C) ? h[(size_t)(b * N + n0 + r) * hstride + gc] : 0.f;
      }
      for (int i = tid; i < 128 * CW; i += 256) {
        int c = i & 15, r = i >> 4;
        int gc = cc + c;
        Bst[c][r] = (gc < C) ? h[(size_t)(b * N + m0 + r) * hstride + gc] : 0.f;
      }
    }
    __syncthreads();
    if (tid < 64) {
#pragma unroll
      for (int c = 0; c < CW; ++c) { float v = Ast[c][tid]; sqa += v * v; }
    } else if (tid < 192) {
      int r = tid - 64;
#pragma unroll
      for (int c = 0; c < CW; ++c) { float v = Bst[c][r]; sqa += v * v; }
    }
#pragma unroll
    for (int c = 0; c < CW; ++c) {
      float4 a0 = *reinterpret_cast<const float4*>(&Ast[c][ty * 4]);
      float4 b0 = *reinterpret_cast<const float4*>(&Bst[c][tx * 4]);
      float4 b1 = *reinterpret_cast<const float4*>(&Bst[c][64 + tx * 4]);
      float av[4] = {a0.x, a0.y, a0.z, a0.w};
      float bv[8] = {b0.x, b0.y, b0.z, b0.w, b1.x, b1.y, b1.z, b1.w};
#pragma unroll
      for (int i = 0; i < 4; ++i)
#pragma unroll
        for (int j = 0; j < 8; ++j) dot[i][j] += av[i] * bv[j];
    }
    __syncthreads();
  }
  if (tid < 64) sqn[tid] = sqa;
  else if (tid < 192) sqm[tid - 64] = sqa;
  __syncthreads();
#pragma unroll
  for (int i = 0; i < 4; ++i) {
    int nn = n0 + ty * 4 + i;
    float sn = sqn[ty * 4 + i];
    float4 w;
    w.x = sn + sqm[tx * 4 + 0] - 2.f * dot[i][0];
    w.y = sn + sqm[tx * 4 + 1] - 2.f * dot[i][1];
    w.z = sn + sqm[tx * 4 + 2] - 2.f * dot[i][2];
    w.w = sn + sqm[tx * 4 + 3] - 2.f * dot[i][3];
    *reinterpret_cast<float4*>(&dist[(size_t)(b * N + nn) * N + m0 + tx * 4]) = w;
    float4 w2;
    w2.x = sn + sqm[64 + tx * 4 + 0] - 2.f * dot[i][4];
    w2.y = sn + sqm[64 + tx * 4 + 1] - 2.f * dot[i][5];
    w2.z = sn + sqm[64 + tx * 4 + 2] - 2.f * dot[i][6];
    w2.w = sn + sqm[64 + tx * 4 + 3] - 2.f * dot[i][7];
    *reinterpret_cast<float4*>(&dist[(size_t)(b * N + nn) * N + m0 + 64 + tx * 4]) = w2;
  }
}

__device__ __forceinline__ unsigned long long wave_min_u64(unsigned long long v) {
#pragma unroll
  for (int m = 1; m < 64; m <<= 1) {
    unsigned lo = (unsigned)v;
    unsigned hi = (unsigned)(v >> 32);
    unsigned olo = (unsigned)__shfl_xor((int)lo, m, 64);
    unsigned ohi = (unsigned)__shfl_xor((int)hi, m, 64);
    unsigned long long ov = ((unsigned long long)ohi << 32) | olo;
    if (ov < v) v = ov;
  }
  return v;
}

#define ARGMIN32(dk, ld, lj)                                        \
  {                                                                 \
    unsigned kv0 = dk[0], kv1 = dk[8], kv2 = dk[16], kv3 = dk[24];  \
    int j0 = 0, j1 = 8, j2 = 16, j3 = 24;                           \
    _Pragma("unroll")                                               \
    for (int t = 1; t < 8; ++t) {                                   \
      if (dk[t] < kv0) { kv0 = dk[t]; j0 = t; }                     \
      if (dk[8 + t] < kv1) { kv1 = dk[8 + t]; j1 = 8 + t; }         \
      if (dk[16 + t] < kv2) { kv2 = dk[16 + t]; j2 = 16 + t; }      \
      if (dk[24 + t] < kv3) { kv3 = dk[24 + t]; j3 = 24 + t; }      \
    }                                                               \
    if (kv1 < kv0) { kv0 = kv1; j0 = j1; }                          \
    if (kv3 < kv2) { kv2 = kv3; j2 = j3; }                          \
    if (kv2 < kv0) { kv0 = kv2; j0 = j2; }                          \
    ld = kv0; lj = j0;                                              \
  }

// 64-lane bitonic sort, ascending toward lane 0 (u32 keys).
__device__ __forceinline__ unsigned bitonic64_u32(unsigned v, int lane) {
#pragma unroll
  for (int k = 2; k <= 64; k <<= 1) {
#pragma unroll
    for (int j = k >> 1; j > 0; j >>= 1) {
      unsigned o = (unsigned)__shfl_xor((int)v, j, 64);
      bool up = (lane & k) == 0;
      bool lower = (lane & j) == 0;
      bool keepmin = (up == lower);
      unsigned mn = v < o ? v : o;
      unsigned mx = v < o ? o : v;
      v = keepmin ? mn : mx;
    }
  }
  return v;
}

// 64-lane bitonic sort of (hi,lo) u64 keys, ascending lexicographic toward lane 0.
__device__ __forceinline__ void bitonic64_u64(unsigned& hi, unsigned& lo, int lane) {
#pragma unroll
  for (int k = 2; k <= 64; k <<= 1) {
#pragma unroll
    for (int j = k >> 1; j > 0; j >>= 1) {
      unsigned ohi = (unsigned)__shfl_xor((int)hi, j, 64);
      unsigned olo = (unsigned)__shfl_xor((int)lo, j, 64);
      bool up = (lane & k) == 0;
      bool lower = (lane & j) == 0;
      bool keepmin = (up == lower);
      bool lt = (hi < ohi) || (hi == ohi && lo < olo);  // self < other
      bool take_other = keepmin ? !lt : lt;
      if (take_other) { hi = ohi; lo = olo; }
    }
  }
}

// ---------------------------------------------------------------- fused select || proj
// R19 select: filter+sort. T = rank-32 of the 64 sorted lane-mins bounds the
// true 33rd-smallest; compact survivors (~46 expected) into a 64-slot LDS
// arena; one u64 bitonic sort emits neighbors. Exact (bitwise-identical);
// survivors>64 -> iterative fallback with block-uniform barriers.
template <int C, int NO2>
__global__ __launch_bounds__(256) void selproj_kernel(const float* __restrict__ dist,
                                                      int* __restrict__ idxb,
                                                      const float* __restrict__ h,
                                                      int hstride,
                                                      const float* __restrict__ Wp,
                                                      float* __restrict__ projb) {
  constexpr int NSEL = B * N / 4;
  constexpr int MT = NO2 / 64;
  constexpr int CW = 16;
  __shared__ float As[64][17];
  __shared__ float Bs[64][17];
  if (blockIdx.x < NSEL) {
    int row = blockIdx.x * 4 + (threadIdx.x >> 6);  // b*N + n
    int lane = threadIdx.x & 63;
    const float* drow = dist + (size_t)row * N;
    unsigned dk[32];
#pragma unroll
    for (int j = 0; j < 32; ++j) {
      unsigned u = __float_as_uint(drow[j * 64 + lane]);
      dk[j] = (u & 0x80000000u) ? ~u : (u | 0x80000000u);
    }
    // ---- threshold T = rank-32 of the 64 lane-mins ----
    unsigned lmin0 = dk[0], lmin1 = dk[1];
#pragma unroll
    for (int j = 2; j < 32; j += 2) {
      lmin0 = lmin0 < dk[j] ? lmin0 : dk[j];
      lmin1 = lmin1 < dk[j + 1] ? lmin1 : dk[j + 1];
    }
    unsigned lmin = lmin0 < lmin1 ? lmin0 : lmin1;
    unsigned srt = bitonic64_u32(lmin, lane);
    unsigned T = (unsigned)__shfl((int)srt, 32, 64);
    // ---- count survivors + prefix offsets ----
    unsigned cnt = 0;
#pragma unroll
    for (int j = 0; j < 32; ++j) cnt += (dk[j] <= T) ? 1u : 0u;
    unsigned inc = cnt;
#pragma unroll
    for (int d = 1; d < 64; d <<= 1) {
      unsigned t = (unsigned)__shfl_up((int)inc, d, 64);
      if (lane >= d) inc += t;
    }
    unsigned tot = (unsigned)__shfl((int)inc, 63, 64);
    unsigned off = inc - cnt;
    bool fast = tot <= 64u;  // wave-uniform
    unsigned* aHi = reinterpret_cast<unsigned*>(&As[0][0]);
    unsigned* aLo = reinterpret_cast<unsigned*>(&Bs[0][0]);
    int wbase = (threadIdx.x >> 6) * 64;
    aHi[wbase + lane] = 0xFFFFFFFFu;
    aLo[wbase + lane] = 0xFFFFFFFFu;
    __syncthreads();
    if (fast) {
      unsigned o = off;
#pragma unroll
      for (int j = 0; j < 32; ++j) {
        if (dk[j] <= T) {
          aHi[wbase + o] = dk[j];
          aLo[wbase + o] = (unsigned)(j * 64 + lane);
          ++o;
        }
      }
    }
    __syncthreads();
    if (fast) {
      unsigned hi = aHi[wbase + lane];
      unsigned lo = aLo[wbase + lane];
      bitonic64_u64(hi, lo, lane);
      if (lane >= 1 && lane <= KNN) idxb[row * KNN + lane - 1] = (int)lo;
    } else {
      unsigned ld;
      int lj;
      ARGMIN32(dk, ld, lj);
      unsigned saved = 0;
      for (int it = 0; it <= KNN; ++it) {
        unsigned long long lkey =
            ((unsigned long long)ld << 32) | (unsigned)(lj * 64 + lane);
        unsigned long long g = wave_min_u64(lkey);
        if (it > 0 && lane == it - 1) saved = (unsigned)(g & 0xFFFFFFFFull);
        if (lkey == g) {
#pragma unroll
          for (int j = 0; j < 32; ++j)
            if (j == lj) dk[j] = 0xFFFFFFFFu;
          ARGMIN32(dk, ld, lj);
        }
      }
      if (lane < KNN) idxb[row * KNN + lane] = (int)saved;
    }
  } else {
    int tile = blockIdx.x - NSEL;
    int m0 = (tile % MT) * 64;
    int n0 = (tile / MT) * 64;
    int tid = threadIdx.x;
    int tx = tid & 15, ty = tid >> 4;
    float dot[4][4] = {};
    for (int cc = 0; cc < C; cc += CW) {
      for (int i = tid; i < 64 * CW; i += 256) {
        int r = i >> 4, c = i & 15;
        int gc = cc + c;
        As[r][c] = (gc < C) ? h[(size_t)(n0 + r) * hstride + gc] : 0.f;
      }
      for (int i = tid; i < 64 * CW; i += 256) {
        int c = i >> 6, m = i & 63;
        int gc = cc + c;
        Bs[m][c] = (gc < C) ? Wp[(size_t)gc * NO2 + m0 + m] : 0.f;
      }
      __syncthreads();
#pragma unroll
      for (int c = 0; c < CW; ++c) {
        float av[4], bv[4];
#pragma unroll
        for (int i = 0; i < 4; ++i) av[i] = As[ty * 4 + i][c];
#pragma unroll
        for (int j = 0; j < 4; ++j) bv[j] = Bs[tx * 4 + j][c];
#pragma unroll
        for (int i = 0; i < 4; ++i)
#pragma unroll
          for (int j = 0; j < 4; ++j) dot[i][j] += av[i] * bv[j];
      }
      __syncthreads();
    }
#pragma unroll
    for (int i = 0; i < 4; ++i) {
      float4 wv;
      wv.x = dot[i][0];
      wv.y = dot[i][1];
      wv.z = dot[i][2];
      wv.w = dot[i][3];
      int m = m0 + tx * 4;  // m&15 in {0,4,8,12}: float4 stays within one slab
      size_t base = ((size_t)(m >> 4) * (B * N) + (size_t)(n0 + ty * 4 + i)) * 16 + (m & 15);
      *reinterpret_cast<float4*>(&projb[base]) = wv;
    }
  }
}

// ---------------------------------------------------------------- edge reduce (slab)
template <int O, int NP>
__global__ __launch_bounds__(256) void edge_slab_kernel(const float* __restrict__ projs,
                                                        const int* __restrict__ idxb,
                                                        float* __restrict__ cstats,
                                                        float* __restrict__ featdst) {
  __shared__ float slab[2048 * 16];  // 128 KB
  __shared__ float redsm[2][4][16];
  int split = blockIdx.x, s = blockIdx.y, b = blockIdx.z;
  int tid = threadIdx.x, w = tid >> 6, lane = tid & 63;
  int kq = lane >> 4, ch = lane & 15;
  {
    const float4* src =
        (const float4*)(projs + ((size_t)s * (B * N) + (size_t)b * N) * 16);
    float4* dst = (float4*)slab;
#pragma unroll
    for (int i = 0; i < 32; ++i) dst[tid + i * 256] = src[tid + i * 256];
  }
  __syncthreads();
  const float* h0s = projs + (size_t)(O / 16 + s) * (B * N) * 16;
  int bn0 = b * N + split * NP;
  constexpr int NPW = NP / 4;
  float sum = 0.f, ssum = 0.f;
  int bn = bn0 + w;
  int4 j0n = *(const int4*)(idxb + (size_t)bn * KNN + kq * 8);
  int4 j1n = *(const int4*)(idxb + (size_t)bn * KNN + kq * 8 + 4);
  float h0n = h0s[(size_t)bn * 16 + ch];
  for (int p = 0; p < NPW; ++p) {
    int4 j0 = j0n, j1 = j1n;
    float h0 = h0n;
    int bncur = bn;
    if (p + 1 < NPW) {
      bn = bn0 + (p + 1) * 4 + w;
      j0n = *(const int4*)(idxb + (size_t)bn * KNN + kq * 8);
      j1n = *(const int4*)(idxb + (size_t)bn * KNN + kq * 8 + 4);
      h0n = h0s[(size_t)bn * 16 + ch];
    }
    float a0 = slab[j0.x * 16 + ch];
    float a1 = slab[j0.y * 16 + ch];
    float a2 = slab[j0.z * 16 + ch];
    float a3 = slab[j0.w * 16 + ch];
    float a4 = slab[j1.x * 16 + ch];
    float a5 = slab[j1.y * 16 + ch];
    float a6 = slab[j1.z * 16 + ch];
    float a7 = slab[j1.w * 16 + ch];
    float e0 = a0 + h0, e1 = a1 + h0, e2 = a2 + h0, e3 = a3 + h0;
    float e4 = a4 + h0, e5 = a5 + h0, e6 = a6 + h0, e7 = a7 + h0;
    sum += e0 + e1 + e2 + e3 + e4 + e5 + e6 + e7;
    ssum += e0 * e0 + e1 * e1 + e2 * e2 + e3 * e3 + e4 * e4 + e5 * e5 + e6 * e6 + e7 * e7;
    float mx = fmaxf(fmaxf(fmaxf(e0, e1), fmaxf(e2, e3)), fmaxf(fmaxf(e4, e5), fmaxf(e6, e7)));
    mx = fmaxf(mx, __shfl_xor(mx, 16, 64));
    mx = fmaxf(mx, __shfl_xor(mx, 32, 64));
    if (kq == 0) featdst[(size_t)bncur * FD + s * 16 + ch] = mx;
  }
  sum += __shfl_xor(sum, 16, 64);
  sum += __shfl_xor(sum, 32, 64);
  ssum += __shfl_xor(ssum, 16, 64);
  ssum += __shfl_xor(ssum, 32, 64);
  if (kq == 0) {
    redsm[0][w][ch] = sum;
    redsm[1][w][ch] = ssum;
  }
  __syncthreads();
  if (tid < 16) {
    float S = 0.f, SS = 0.f;
#pragma unroll
    for (int r = 0; r < 4; ++r) {
      S += redsm[0][r][tid];
      SS += redsm[1][r][tid];
    }
    int rep = split & (REP - 1);
    float* cs = cstats + ((size_t)rep * B + b) * O * 2 + (size_t)(s * 16 + tid) * 2;
    atomicAdd(&cs[0], S);
    atomicAdd(&cs[1], SS);
  }
}

// in-place: featdst = lrelu((featdst - mean) * rsqrt(var + eps)); folds REP replicas
__global__ void finalize_kernel(const float* __restrict__ cstats,
                                float* __restrict__ featdst, int O) {
  int i = blockIdx.x * 256 + threadIdx.x;
  int o = i % O;
  int bn = i / O;
  int b = bn >> 11;
  float s = 0.f, ss = 0.f;
#pragma unroll
  for (int r = 0; r < REP; ++r) {
    s += cstats[(size_t)r * (B * O * 2) + (size_t)(b * O + o) * 2 + 0];
    ss += cstats[(size_t)r * (B * O * 2) + (size_t)(b * O + o) * 2 + 1];
  }
  constexpr float inv = 1.f / ((float)N * KNN);
  float m = s * inv;
  float v = fmaxf(ss * inv - m * m, 0.f);
  float* p = &featdst[(size_t)bn * FD + o];
  float e = (*p - m) * rsqrtf(v + EPS);
  *p = lrelu(e);
}

// ---------------------------------------------------------------- 480 -> 128 stage
__global__ __launch_bounds__(256) void fstage_kernel(const float* __restrict__ feats,
                                                     const float* __restrict__ Wht,
                                                     float* __restrict__ fsum,
                                                     float* __restrict__ fss,
                                                     unsigned* __restrict__ fmaxu) {
  int blk = blockIdx.x;
  int b = blk >> 7;
  int n0 = (blk & 127) * 16;
  int tid = threadIdx.x;
  __shared__ float rows[16][FD];
  __shared__ float red[3][2][128];
  for (int i = tid; i < 16 * FD; i += 256) {
    int r = i / FD, c = i - r * FD;
    rows[r][c] = feats[(size_t)(b * N + n0 + r) * FD + c];
  }
  __syncthreads();
  int o = tid & 127, g = tid >> 7;
  float acc[8] = {};
  for (int c = 0; c < FD; c += 4) {
    float w0 = Wht[(c + 0) * 128 + o];
    float w1 = Wht[(c + 1) * 128 + o];
    float w2 = Wht[(c + 2) * 128 + o];
    float w3 = Wht[(c + 3) * 128 + o];
#pragma unroll
    for (int j = 0; j < 8; ++j) {
      float4 r4 = *reinterpret_cast<const float4*>(&rows[g * 8 + j][c]);
      acc[j] += w0 * r4.x + w1 * r4.y + w2 * r4.z + w3 * r4.w;
    }
  }
  float s = 0.f, ss = 0.f, mx = -3.4e38f;
#pragma unroll
  for (int j = 0; j < 8; ++j) {
    float f = acc[j];
    s += f;
    ss += f * f;
    mx = fmaxf(mx, f);
  }
  red[0][g][o] = s;
  red[1][g][o] = ss;
  red[2][g][o] = mx;
  __syncthreads();
  if (g == 0) {
    s += red[0][1][o];
    ss += red[1][1][o];
    mx = fmaxf(mx, red[2][1][o]);
    atomicAdd(&fsum[b * 128 + o], s);
    atomicAdd(&fss[b * 128 + o], ss);
    unsigned u = __float_as_uint(mx);
    u = (u & 0x80000000u) ? ~u : (u | 0x80000000u);
    atomicMax(&fmaxu[b * 128 + o], u);
  }
}

// ---------------------------------------------------------------- head
__global__ __launch_bounds__(128) void head_kernel(const float* __restrict__ fsum,
                                                   const float* __restrict__ fss,
                                                   const unsigned* __restrict__ fmaxu,
                                                   const float* __restrict__ fc1w,
                                                   const float* __restrict__ fc1b,
                                                   const float* __restrict__ fc2w,
                                                   const float* __restrict__ fc2b,
                                                   void* __restrict__ out,
                                                   const int* __restrict__ flag) {
  int b = blockIdx.x, o = threadIdx.x;
  __shared__ float gs[128], t1[128], ys[128];
  constexpr float invN = 1.f / N;
  float m = fsum[b * 128 + o] * invN;
  float v = fmaxf(fss[b * 128 + o] * invN - m * m, 0.f);
  unsigned u = fmaxu[b * 128 + o];
  unsigned bits = (u & 0x80000000u) ? (u ^ 0x80000000u) : ~u;
  float fx = __uint_as_float(bits);
  gs[o] = lrelu((fx - m) * rsqrtf(v + EPS));
  __syncthreads();
  float a = fc1b[o];
  for (int c = 0; c < 128; ++c) a += fc1w[o * 128 + c] * gs[c];
  t1[o] = a;
  __syncthreads();
  float mm = 0.f;
  for (int c = 0; c < 128; ++c) mm += t1[c];
  mm *= (1.f / 128);
  float vv = 0.f;
  for (int c = 0; c < 128; ++c) {
    float d = t1[c] - mm;
    vv += d * d;
  }
  vv *= (1.f / 128);
  ys[o] = lrelu((a - mm) * rsqrtf(vv + EPS));
  __syncthreads();
  float r = fc2b[o];
  for (int c = 0; c < 128; ++c) r += fc2w[o * 128 + c] * ys[c];
  if (flag[0])
    ((float*)out)[b * 128 + o] = r;
  else
    ((bf16*)out)[b * 128 + o] = __float2bfloat16(r);
}

// ---------------------------------------------------------------- driver
template <int C, int O>
static void run_layer(const float* h, int hstride, float* featdst, const float* Wp,
                      float* cstats, float* dist, float* projb, int* idxb,
                      hipStream_t stream) {
  constexpr int NSEL = B * N / 4;
  constexpr int NPROJ = (2 * O / 64) * (B * N / 64);
  dist_kernel<C><<<dim3(N / 128, N / 64, B), 256, 0, stream>>>(h, hstride, dist);
  selproj_kernel<C, 2 * O><<<NSEL + NPROJ, 256, 0, stream>>>(dist, idxb, h, hstride, Wp,
                                                             projb);
  constexpr int NP = (O >= 256) ? 256 : (O == 128 ? 128 : 64);
  edge_slab_kernel<O, NP><<<dim3(N / NP, O / 16, B), 256, 0, stream>>>(projb, idxb, cstats,
                                                                       featdst);
  finalize_kernel<<<B * N * O / 256, 256, 0, stream>>>(cstats, featdst, O);
}

extern "C" void kernel_launch(void* const* d_in, const int* in_sizes, int n_in,
                              void* d_out, int out_size, void* d_ws, size_t ws_size,
                              hipStream_t stream) {
  float* ws = (float*)d_ws;
  float* xf = ws + O_XF;
  float* feats = ws + O_FEATS;
  float* dist = ws + O_DIST;
  float* projb = ws + O_PROJ;
  int* idxb = (int*)(ws + O_IDX);
  int* flag = (int*)(ws + O_FLAG);

  prep_kernel<<<(PREP_TOTAL + 255) / 256, 256, 0, stream>>>(
      d_in[0], d_in[2], d_in[3], d_in[4], d_in[5], d_in[6], d_in[7], d_in[8], d_in[9],
      d_in[10], ws);

  run_layer<3, 32>(xf, 3, feats + 0, ws + O_WP0, ws + O_CS0, dist, projb, idxb, stream);
  run_layer<32, 64>(feats + 0, FD, feats + 32, ws + O_WP1, ws + O_CS1, dist, projb, idxb,
                    stream);
  run_layer<64, 128>(feats + 32, FD, feats + 96, ws + O_WP2, ws + O_CS2, dist, projb, idxb,
                     stream);
  run_layer<128, 256>(feats + 96, FD, feats + 224, ws + O_WP3, ws + O_CS3, dist, projb,
                      idxb, stream);

  fstage_kernel<<<B * 128, 256, 0, stream>>>(feats, ws + O_WHT, ws + O_FSUM, ws + O_FSS,
                                             (unsigned*)(ws + O_FMAX));
  head_kernel<<<B, 128, 0, stream>>>(ws + O_FSUM, ws + O_FSS, (unsigned*)(ws + O_FMAX),
                                     ws + O_F1W, ws + O_F1B, ws + O_F2W, ws + O_F2B, d_out,
                                     flag);
}